// Round 11
// baseline (635.042 us; speedup 1.0000x reference)
//
#include <hip/hip_runtime.h>
#include <hip/hip_bf16.h>

#define Ee 1024
#define Hh 16
#define Ff 4608
#define Ll 4096
#define Bb 2
#define NCc 16
#define CHk 256

typedef short bf16x8 __attribute__((ext_vector_type(8)));
typedef float f32x4 __attribute__((ext_vector_type(4)));

#define GLD16(g, l) __builtin_amdgcn_global_load_lds( \
    (const __attribute__((address_space(1))) unsigned int*)(g), \
    (__attribute__((address_space(3))) unsigned int*)(l), 16, 0, 0)
#define SCHED0() __builtin_amdgcn_sched_barrier(0)
#define SBAR()   __builtin_amdgcn_s_barrier()
#define MFMA16(a,b,c) __builtin_amdgcn_mfma_f32_16x16x32_bf16(a,b,c,0,0,0)

__device__ __forceinline__ unsigned short f2bf(float f){
  unsigned int u = __builtin_bit_cast(unsigned int, f);
  u += 0x7fffu + ((u >> 16) & 1u);
  return (unsigned short)(u >> 16);
}
__device__ __forceinline__ float bf2f(unsigned short h){
  unsigned int u = ((unsigned int)h) << 16;
  return __builtin_bit_cast(float, u);
}
__device__ __forceinline__ float fixv(float v){
  return (__builtin_isnan(v) || __builtin_isinf(v)) ? 0.f : v;
}

// ---------------- weight convert+transpose: W[K][N] fp32 -> WT[mapped n][K] bf16 ----------------
// gu=0: identity rows. gu=1: gate rows ((n>>7)*256 + (n&127)). gu=2: up rows (+128).
__global__ __launch_bounds__(256) void wconv_kernel(const float* __restrict__ W,
    unsigned short* __restrict__ WT, int K, int N, const float* __restrict__ scale, int gu){
  __shared__ unsigned short T[64][72];
  int k0 = blockIdx.y*64, n0 = blockIdx.x*64;
  int t = threadIdx.x;
  int kr = t>>4, n4 = (t&15)*4;
  #pragma unroll
  for (int it=0; it<4; it++){
    int k = kr + it*16;
    float s = scale ? scale[k0+k] : 1.f;
    float4 v = *(const float4*)(W + (size_t)(k0+k)*N + n0 + n4);
    T[n4+0][k] = f2bf(v.x*s);
    T[n4+1][k] = f2bf(v.y*s);
    T[n4+2][k] = f2bf(v.z*s);
    T[n4+3][k] = f2bf(v.w*s);
  }
  __syncthreads();
  int u = t&7;
  #pragma unroll
  for (int it=0; it<2; it++){
    int n = (t>>3) + it*32;
    int nn = n0 + n;
    int nout = nn;
    if (gu) nout = ((nn>>7)<<8) + (nn&127) + ((gu==2)?128:0);
    *(bf16x8*)(WT + (size_t)nout*K + k0 + u*8) = *(const bf16x8*)&T[n][u*8];
  }
}

// ---------------- RMSNorm fp32 in -> bf16 out ----------------
__global__ __launch_bounds__(256) void rmsnorm_kernel(const float* __restrict__ x,
    const float* __restrict__ g, unsigned short* __restrict__ out){
  int row = blockIdx.x; int t = threadIdx.x;
  float4 v = ((const float4*)(x + (size_t)row*Ee))[t];
  v.x=fixv(v.x); v.y=fixv(v.y); v.z=fixv(v.z); v.w=fixv(v.w);
  float ss = v.x*v.x + v.y*v.y + v.z*v.z + v.w*v.w;
  #pragma unroll
  for (int off=32; off>0; off>>=1) ss += __shfl_down(ss, off);
  __shared__ float red[4];
  if ((t&63)==0) red[t>>6] = ss;
  __syncthreads();
  float tot = red[0]+red[1]+red[2]+red[3];
  float rms = sqrtf(tot*(1.f/Ee) + 1e-6f);
  rms = fminf(fmaxf(rms, 1e-6f), 1e6f);
  float inv = 1.f/rms;
  float4 gv = ((const float4*)g)[t];
  uint2 o;
  o.x = (unsigned)f2bf(v.x*inv*gv.x) | ((unsigned)f2bf(v.y*inv*gv.y)<<16);
  o.y = (unsigned)f2bf(v.z*inv*gv.z) | ((unsigned)f2bf(v.w*inv*gv.w)<<16);
  ((uint2*)(out + (size_t)row*Ee))[t] = o;
}

// ================ phase-interleaved 256x256 GEMM core pieces ================
// 8 waves 2Mx4N, wave tile 128x64, BK=32, 4-buffer LDS rotation (128KB),
// 2 phases per K-tile (by M-half), B-frags register-reused across phases,
// 2 GLD16/thread/phase staging, counted vmcnt (8/4/0), raw barriers.

// ---------------- plain: C bf16 (qkv) ----------------
__global__ __launch_bounds__(512) void gemm8p_kernel(
    const unsigned short* __restrict__ A, const unsigned short* __restrict__ Bt,
    unsigned short* __restrict__ C, int M, int N, int K){
  __shared__ __align__(16) unsigned short S[65536];   // 4 bufs x 16384 shorts (A 8192 | B 8192)
  int tid = threadIdx.x;
  int nbx = gridDim.x;
  int id = blockIdx.y*nbx + blockIdx.x;
  int chunk = (nbx*gridDim.y) >> 3;
  int wg = (id&7)*chunk + (id>>3);
  int m0 = (wg/nbx)*256, n0 = (wg%nbx)*256;
  int lane = tid&63, wave = tid>>6;
  int wm = (wave>>2)*128, wn = (wave&3)*64;
  int lrow = lane&15, lg = lane>>4;
  int lksw = (lg ^ ((lrow>>1)&3))*8;
  int nk = K>>5;
  int srow = tid>>2;
  int scg = ((tid&3) ^ ((tid>>3)&3))*8;
  const unsigned short* aA0 = A  + (size_t)(m0 + srow)*K + scg;
  const unsigned short* aA1 = A  + (size_t)(m0 + 128 + srow)*K + scg;
  const unsigned short* aB0 = Bt + (size_t)(n0 + srow)*K + scg;
  const unsigned short* aB1 = Bt + (size_t)(n0 + 128 + srow)*K + scg;
  int dA0 = wave*512, dA1 = 4096 + wave*512;
  int dB0 = 8192 + wave*512, dB1 = 12288 + wave*512;
  f32x4 acc[8][4] = {};
  #pragma unroll
  for (int p=0;p<3;p++){
    int ko = p<<5; int bb = p*16384;
    GLD16(aA0+ko, &S[bb+dA0]); GLD16(aA1+ko, &S[bb+dA1]);
    GLD16(aB0+ko, &S[bb+dB0]); GLD16(aB1+ko, &S[bb+dB1]);
  }
  SCHED0();
  asm volatile("s_waitcnt vmcnt(8)" ::: "memory");
  SBAR(); SCHED0();
  int cur = 0;
  for (int t=0; t<nk; ++t){
    int sb = ((cur+3)&3)*16384;
    int ko = (t+3)<<5;
    bool stg = (t+3 < nk);
    int rb = cur*16384;
    bf16x8 bf[4], af[4];
    #pragma unroll
    for (int j=0;j<4;j++) bf[j] = *(const bf16x8*)&S[rb + 8192 + (wn + j*16 + lrow)*32 + lksw];
    #pragma unroll
    for (int i=0;i<4;i++) af[i] = *(const bf16x8*)&S[rb + (wm + i*16 + lrow)*32 + lksw];
    if (stg){ GLD16(aA0+ko, &S[sb+dA0]); GLD16(aA1+ko, &S[sb+dA1]); }
    SCHED0(); SBAR();
    asm volatile("s_waitcnt lgkmcnt(0)" ::: "memory");
    SCHED0();
    __builtin_amdgcn_s_setprio(1);
    #pragma unroll
    for (int i=0;i<4;i++)
      #pragma unroll
      for (int j=0;j<4;j++)
        acc[i][j] = MFMA16(af[i], bf[j], acc[i][j]);
    __builtin_amdgcn_s_setprio(0);
    SCHED0(); SBAR();
    #pragma unroll
    for (int i=0;i<4;i++) af[i] = *(const bf16x8*)&S[rb + (wm + 64 + i*16 + lrow)*32 + lksw];
    if (stg){ GLD16(aB0+ko, &S[sb+dB0]); GLD16(aB1+ko, &S[sb+dB1]); }
    SCHED0();
    if (t+3 < nk)      asm volatile("s_waitcnt vmcnt(8)" ::: "memory");
    else if (t+2 < nk) asm volatile("s_waitcnt vmcnt(4)" ::: "memory");
    else               asm volatile("s_waitcnt vmcnt(0)" ::: "memory");
    SBAR();
    asm volatile("s_waitcnt lgkmcnt(0)" ::: "memory");
    SCHED0();
    __builtin_amdgcn_s_setprio(1);
    #pragma unroll
    for (int i=0;i<4;i++)
      #pragma unroll
      for (int j=0;j<4;j++)
        acc[4+i][j] = MFMA16(af[i], bf[j], acc[4+i][j]);
    __builtin_amdgcn_s_setprio(0);
    SCHED0(); SBAR();
    cur = (cur+1)&3;
  }
  #pragma unroll
  for (int mi=0;mi<8;mi++){
    #pragma unroll
    for (int r=0;r<4;r++){
      int row = m0 + wm + mi*16 + lg*4 + r;
      #pragma unroll
      for (int ni=0;ni<4;ni++){
        int col = n0 + wn + ni*16 + lrow;
        C[(size_t)row*N + col] = f2bf(acc[mi][ni][r]);
      }
    }
  }
}

// ---------------- gateup via interleaved [G|U] B: hidden = silu(g)*u masked + sumsq ----------------
__global__ __launch_bounds__(512) void gateup8p_kernel(
    const unsigned short* __restrict__ A, const unsigned short* __restrict__ GUt,
    unsigned short* __restrict__ Hid, const float* __restrict__ scal,
    float* __restrict__ sumsq){
  __shared__ __align__(16) unsigned short S[65536];
  int tid = threadIdx.x;
  int nbx = gridDim.x;   // 9216/256 = 36
  int id = blockIdx.y*nbx + blockIdx.x;
  int chunk = (nbx*gridDim.y) >> 3;
  int wg = (id&7)*chunk + (id>>3);
  int m0 = (wg/nbx)*256, n0 = (wg%nbx)*256;
  int n0r = (n0>>8)*128;           // real col base of this tile
  int size = (int)scal[0];
  if (n0r >= size){
    int r = tid >> 1, cb = n0r + (tid&1)*64;
    unsigned short* hp = Hid + (size_t)(m0+r)*Ff + cb;
    bf16x8 z = {};
    #pragma unroll
    for (int i=0;i<8;i++) *(bf16x8*)(hp + i*8) = z;
    return;
  }
  int lane = tid&63, wave = tid>>6;
  int wm = (wave>>2)*128, wn = (wave&3)*64;
  int lrow = lane&15, lg = lane>>4;
  int lksw = (lg ^ ((lrow>>1)&3))*8;
  const int K = Ee, nk = Ee>>5;
  int srow = tid>>2;
  int scg = ((tid&3) ^ ((tid>>3)&3))*8;
  const unsigned short* aA0 = A   + (size_t)(m0 + srow)*K + scg;
  const unsigned short* aA1 = A   + (size_t)(m0 + 128 + srow)*K + scg;
  const unsigned short* aB0 = GUt + (size_t)(n0 + srow)*K + scg;
  const unsigned short* aB1 = GUt + (size_t)(n0 + 128 + srow)*K + scg;
  int dA0 = wave*512, dA1 = 4096 + wave*512;
  int dB0 = 8192 + wave*512, dB1 = 12288 + wave*512;
  f32x4 acc[8][4] = {};
  #pragma unroll
  for (int p=0;p<3;p++){
    int ko = p<<5; int bb = p*16384;
    GLD16(aA0+ko, &S[bb+dA0]); GLD16(aA1+ko, &S[bb+dA1]);
    GLD16(aB0+ko, &S[bb+dB0]); GLD16(aB1+ko, &S[bb+dB1]);
  }
  SCHED0();
  asm volatile("s_waitcnt vmcnt(8)" ::: "memory");
  SBAR(); SCHED0();
  int cur = 0;
  for (int t=0; t<nk; ++t){
    int sb = ((cur+3)&3)*16384;
    int ko = (t+3)<<5;
    bool stg = (t+3 < nk);
    int rb = cur*16384;
    bf16x8 bf[4], af[4];
    #pragma unroll
    for (int j=0;j<4;j++) bf[j] = *(const bf16x8*)&S[rb + 8192 + (wn + j*16 + lrow)*32 + lksw];
    #pragma unroll
    for (int i=0;i<4;i++) af[i] = *(const bf16x8*)&S[rb + (wm + i*16 + lrow)*32 + lksw];
    if (stg){ GLD16(aA0+ko, &S[sb+dA0]); GLD16(aA1+ko, &S[sb+dA1]); }
    SCHED0(); SBAR();
    asm volatile("s_waitcnt lgkmcnt(0)" ::: "memory");
    SCHED0();
    __builtin_amdgcn_s_setprio(1);
    #pragma unroll
    for (int i=0;i<4;i++)
      #pragma unroll
      for (int j=0;j<4;j++)
        acc[i][j] = MFMA16(af[i], bf[j], acc[i][j]);
    __builtin_amdgcn_s_setprio(0);
    SCHED0(); SBAR();
    #pragma unroll
    for (int i=0;i<4;i++) af[i] = *(const bf16x8*)&S[rb + (wm + 64 + i*16 + lrow)*32 + lksw];
    if (stg){ GLD16(aB0+ko, &S[sb+dB0]); GLD16(aB1+ko, &S[sb+dB1]); }
    SCHED0();
    if (t+3 < nk)      asm volatile("s_waitcnt vmcnt(8)" ::: "memory");
    else if (t+2 < nk) asm volatile("s_waitcnt vmcnt(4)" ::: "memory");
    else               asm volatile("s_waitcnt vmcnt(0)" ::: "memory");
    SBAR();
    asm volatile("s_waitcnt lgkmcnt(0)" ::: "memory");
    SCHED0();
    __builtin_amdgcn_s_setprio(1);
    #pragma unroll
    for (int i=0;i<4;i++)
      #pragma unroll
      for (int j=0;j<4;j++)
        acc[4+i][j] = MFMA16(af[i], bf[j], acc[4+i][j]);
    __builtin_amdgcn_s_setprio(0);
    SCHED0(); SBAR();
    cur = (cur+1)&3;
  }
  // epilogue: waves q>=2 hold UP acc, waves q<2 hold GATE acc (same cols, same wm).
  float* X = (float*)S;
  int mg = wave>>2, q = wave&3;
  __syncthreads();
  for (int mi=0; mi<8; mi++){
    if (q >= 2){
      int bi = (q-2) + 2*mg;
      #pragma unroll
      for (int r=0;r<4;r++)
        #pragma unroll
        for (int ni=0;ni<4;ni++)
          X[bi*1024 + (lg*4+r)*64 + ni*16 + lrow] = acc[mi][ni][r];
    }
    __syncthreads();
    if (q < 2){
      int bi = q + 2*mg;
      #pragma unroll
      for (int r=0;r<4;r++){
        int row = m0 + wm + mi*16 + lg*4 + r;
        float s4 = 0.f;
        #pragma unroll
        for (int ni=0;ni<4;ni++){
          int col = n0r + q*64 + ni*16 + lrow;
          float g = acc[mi][ni][r];
          float u = X[bi*1024 + (lg*4+r)*64 + ni*16 + lrow];
          float hv = (g * (1.f/(1.f+expf(-g)))) * u;
          if (col >= size) hv = 0.f;
          if (__builtin_isnan(hv) || __builtin_isinf(hv)) hv = 0.f;
          Hid[(size_t)row*Ff + col] = f2bf(hv);
          s4 += hv*hv;
        }
        s4 += __shfl_xor(s4, 1);
        s4 += __shfl_xor(s4, 2);
        s4 += __shfl_xor(s4, 4);
        s4 += __shfl_xor(s4, 8);
        if (lrow == 0) atomicAdd(&sumsq[row], s4);
      }
    }
    __syncthreads();
  }
}

// ---------------- bf16 GEMM (r10 structure) for out-proj / down ----------------
// MODE 1: C fp32 = acc + res. MODE 2: C fp32 = acc*inv_rms(sumsq,klim) + res, K truncated.
template<int MODE>
__global__ __launch_bounds__(512) void gemm_kernel(
    const unsigned short* __restrict__ A, const unsigned short* __restrict__ Bt,
    void* __restrict__ Cv, int M, int N, int K,
    const float* __restrict__ res, const float* __restrict__ rowscale,
    const float* __restrict__ klim){
  __shared__ __align__(16) unsigned short S[36864];
  int tid = threadIdx.x;
  int nbx = gridDim.x;
  int id = blockIdx.y * nbx + blockIdx.x;
  int chunk = (nbx * gridDim.y) >> 3;
  int wg = (id & 7) * chunk + (id >> 3);
  int m0 = (wg / nbx) * 256, n0 = (wg % nbx) * 128;
  int lane = tid & 63, wave = tid >> 6;
  int wm = (wave>>1)*64, wn = (wave&1)*64;
  int lrow = lane & 15;
  int lksw = (((lane>>4) ^ ((lrow>>1)&3)))*8;
  float klim0 = (MODE==2 && klim) ? klim[0] : 0.f;
  int kend = K;
  if (MODE==2 && klim){
    int sz = (int)klim0;
    int ke = ((sz + 31) >> 5) << 5;
    kend = ke < K ? ke : K;
  }
  int nk = kend >> 5;
  int segr = lane >> 2;
  int cg = (((lane&3) ^ ((lane>>3)&3))) * 8;
  const unsigned short* gp[3];
  int loff[3];
  #pragma unroll
  for (int i=0;i<3;i++){
    int g = wave*3 + i;
    if (g < 16){ gp[i] = A  + (size_t)(m0 + g*16 + segr)*K + cg;       loff[i] = g*512; }
    else       { gp[i] = Bt + (size_t)(n0 + (g-16)*16 + segr)*K + cg;  loff[i] = 8192 + (g-16)*512; }
  }
  f32x4 acc[4][4] = {};
  #pragma unroll
  for (int i=0;i<3;i++) GLD16(gp[i], &S[loff[i]]);
  if (nk > 1){
    #pragma unroll
    for (int i=0;i<3;i++) GLD16(gp[i]+32, &S[12288 + loff[i]]);
  }
  SCHED0();
  if (nk > 1) asm volatile("s_waitcnt vmcnt(3)" ::: "memory");
  else        asm volatile("s_waitcnt vmcnt(0)" ::: "memory");
  SBAR(); SCHED0();
  int cur = 0;
  for (int t=0; t<nk; ++t){
    if (t+2 < nk){
      int stg = cur+2; if (stg>=3) stg-=3;
      int ko = (t+2) << 5;
      #pragma unroll
      for (int i=0;i<3;i++) GLD16(gp[i]+ko, &S[stg*12288 + loff[i]]);
    }
    int base = cur*12288;
    bf16x8 af[4], bfr[4];
    #pragma unroll
    for (int i=0;i<4;i++){
      af[i]  = *(const bf16x8*)&S[base + (wm + i*16 + lrow)*32 + lksw];
      bfr[i] = *(const bf16x8*)&S[base + 8192 + (wn + i*16 + lrow)*32 + lksw];
    }
    __builtin_amdgcn_s_setprio(1);
    #pragma unroll
    for (int mi=0;mi<4;mi++)
      #pragma unroll
      for (int ni=0;ni<4;ni++)
        acc[mi][ni] = MFMA16(af[mi], bfr[ni], acc[mi][ni]);
    __builtin_amdgcn_s_setprio(0);
    if (t+1 < nk){
      SCHED0();
      if (t+2 < nk) asm volatile("s_waitcnt vmcnt(3)" ::: "memory");
      else          asm volatile("s_waitcnt vmcnt(0)" ::: "memory");
      SBAR(); SCHED0();
    }
    cur = (cur==2) ? 0 : cur+1;
  }
  int lg = lane >> 4;
  int rbase = m0 + wm + (lg<<2);
  int cbase = n0 + wn + lrow;
  #pragma unroll
  for (int mi=0;mi<4;mi++){
    #pragma unroll
    for (int r=0;r<4;r++){
      int row = rbase + mi*16 + r;
      float rs = 1.f;
      if (MODE==2){
        float rms = sqrtf(rowscale[row]/klim0 + 1e-6f);
        rms = fminf(fmaxf(rms, 1e-6f), 1e6f);
        rs = 1.f/rms;
      }
      #pragma unroll
      for (int ni=0;ni<4;ni++){
        int col = cbase + ni*16;
        float v = acc[mi][ni][r];
        if (MODE==1){
          ((float*)Cv)[(size_t)row*N + col] = v + res[(size_t)row*N + col];
        } else {
          ((float*)Cv)[(size_t)row*N + col] = v*rs + res[(size_t)row*N + col];
        }
      }
    }
  }
}

// ---------------- RoPE + ELU+1 on q,k in bf16 qkv ----------------
__global__ __launch_bounds__(256) void rope_kernel(unsigned short* __restrict__ qkv){
  size_t idx = (size_t)blockIdx.x*256 + threadIdx.x;    // B*L*H*32
  int i = (int)(idx & 31);
  int h = (int)((idx>>5) & 15);
  size_t bl = idx >> 9;
  int pos = (int)(bl & (Ll-1));
  int d0 = 2*i, d1 = d0+1;
  size_t base = bl*3072 + (size_t)h*64 + d0;
  const float LOG1E4_D32 = 0.2878231366242557f;  // ln(10000)/32
  float e0 = (float)(d0 < 32 ? d0 : d0-32);
  float e1 = (float)(d1 < 32 ? d1 : d1-32);
  float f0 = pos * expf(-e0*LOG1E4_D32);
  float f1 = pos * expf(-e1*LOG1E4_D32);
  float s0,c0,s1,c1;
  sincosf(f0,&s0,&c0); sincosf(f1,&s1,&c1);
  unsigned int* qp = (unsigned int*)(qkv + base);
  unsigned int qv = *qp;
  float q0 = bf2f((unsigned short)(qv&0xffff)), q1 = bf2f((unsigned short)(qv>>16));
  float r0 = q0*c0 - q1*s0;
  float r1 = q1*c1 + q0*s1;
  r0 = r0>0.f ? r0+1.f : expf(r0);
  r1 = r1>0.f ? r1+1.f : expf(r1);
  *qp = (unsigned)f2bf(r0) | ((unsigned)f2bf(r1)<<16);
  unsigned int* kp = (unsigned int*)(qkv + base + 1024);
  unsigned int kv = *kp;
  float k0v = bf2f((unsigned short)(kv&0xffff)), k1v = bf2f((unsigned short)(kv>>16));
  float t0 = k0v*c0 - k1v*s0;
  float t1 = k1v*c1 + k0v*s1;
  t0 = t0>0.f ? t0+1.f : expf(t0);
  t1 = t1>0.f ? t1+1.f : expf(t1);
  *kp = (unsigned)f2bf(t0) | ((unsigned)f2bf(t1)<<16);
}

// ---------------- per-chunk K^T V + K col sums via MFMA (ones-column trick) ----------------
__global__ __launch_bounds__(256) void chunksum_kernel(const unsigned short* __restrict__ qkv,
    float* __restrict__ Ssum){
  __shared__ __align__(16) unsigned short Kt[64][72];   // K^T[j][m]
  __shared__ __align__(16) unsigned short Vt[80][72];   // V^T[e][m]; row64=1.0, 65..79=0
  int c = blockIdx.x, bh = blockIdx.y;
  int b = bh >> 4, h = bh & 15;
  int tid = threadIdx.x, lane = tid & 63, wave = tid >> 6;
  int lr = lane & 15, lg = lane >> 4;
  f32x4 acc[5] = {};
  {
    int r16 = tid >> 4, m4 = (tid & 15) * 4;
    unsigned short val = (r16 == 0) ? (unsigned short)0x3F80 : (unsigned short)0;
    #pragma unroll
    for (int u=0; u<4; u++) Vt[64 + r16][m4 + u] = val;
  }
  for (int t=0; t<4; ++t){
    __syncthreads();
    #pragma unroll
    for (int i=0; i<2; i++){
      int tau = tid + i*256;
      int m = tau & 63, dg = (tau >> 6) * 8;
      size_t g = ((size_t)(b*Ll + c*CHk + t*64 + m))*3072 + h*64 + dg;
      bf16x8 kv = *(const bf16x8*)(qkv + g + 1024);
      bf16x8 vv = *(const bf16x8*)(qkv + g + 2048);
      #pragma unroll
      for (int u=0; u<8; u++){
        Kt[dg+u][m] = (unsigned short)kv[u];
        Vt[dg+u][m] = (unsigned short)vv[u];
      }
    }
    __syncthreads();
    #pragma unroll
    for (int kk=0; kk<2; kk++){
      bf16x8 af = *(const bf16x8*)&Kt[wave*16 + lr][kk*32 + lg*8];
      #pragma unroll
      for (int ni=0; ni<5; ni++){
        bf16x8 vf = *(const bf16x8*)&Vt[ni*16 + lr][kk*32 + lg*8];
        acc[ni] = MFMA16(af, vf, acc[ni]);
      }
    }
  }
  float* S = Ssum + ((size_t)bh*NCc + c)*4160;
  int j = wave*16 + lg*4;
  #pragma unroll
  for (int ni=0; ni<4; ni++)
    #pragma unroll
    for (int r=0; r<4; r++)
      S[(size_t)(j+r)*64 + ni*16 + lr] = acc[ni][r];
  if (lr == 0){
    #pragma unroll
    for (int r=0; r<4; r++) S[4096 + j + r] = acc[4][r];
  }
}

// ---------------- exclusive prefix over chunks ----------------
__global__ __launch_bounds__(256) void prefix_kernel(const float* __restrict__ Ssum,
    float* __restrict__ Spre){
  int bh = blockIdx.x; int t = threadIdx.x;
  size_t base = (size_t)bh*NCc*4160;
  for (int e=t; e<4160; e+=256){
    float acc = 0.f;
    #pragma unroll
    for (int c=0;c<NCc;c++){
      Spre[base + (size_t)c*4160 + e] = acc;
      acc += Ssum[base + (size_t)c*4160 + e];
    }
  }
}

// ---------------- per-chunk causal attention via MFMA ----------------
__global__ __launch_bounds__(256, 2) void attnout_kernel(const unsigned short* __restrict__ qkv,
    const float* __restrict__ Spre, unsigned short* __restrict__ attn){
  __shared__ __align__(16) unsigned short SpT[64][72];     // Spre^T[e][j] bf16
  __shared__ __align__(16) unsigned short Ks[64][72];      // K[m][d]
  __shared__ __align__(16) unsigned short Vt[64][72];      // V^T[d][m]
  __shared__ __align__(16) unsigned short P[4][64][72];    // per-wave masked S bf16
  __shared__ float qZd[256];
  int c = blockIdx.x, bh = blockIdx.y;
  int b = bh >> 4, h = bh & 15;
  int tid = threadIdx.x, lane = tid & 63, wave = tid >> 6;
  int lr = lane & 15, lg = lane >> 4;
  const float* Sp = Spre + ((size_t)bh*NCc + c)*4160;

  {
    float zacc = 0.f;
    const unsigned short* qp = qkv + ((size_t)(b*Ll + c*CHk + tid))*3072 + (size_t)h*64;
    #pragma unroll
    for (int g8=0; g8<8; g8++){
      bf16x8 qv = *(const bf16x8*)(qp + g8*8);
      #pragma unroll
      for (int u=0; u<8; u++) zacc += bf2f((unsigned short)qv[u]) * Sp[4096 + g8*8 + u];
    }
    qZd[tid] = zacc;
  }
  #pragma unroll
  for (int i=0; i<2; i++){
    int tau = tid + i*256;
    int j = tau & 63, dg = (tau >> 6) * 8;
    const float* sp = Sp + j*64 + dg;
    #pragma unroll
    for (int u=0; u<8; u++) SpT[dg+u][j] = f2bf(sp[u]);
  }
  bf16x8 af[4][2];
  #pragma unroll
  for (int mi=0; mi<4; mi++){
    size_t qrow = ((size_t)(b*Ll + c*CHk + wave*64 + mi*16 + lr))*3072 + (size_t)h*64;
    #pragma unroll
    for (int kk=0; kk<2; kk++)
      af[mi][kk] = *(const bf16x8*)(qkv + qrow + kk*32 + lg*8);
  }
  __syncthreads();
  f32x4 accO[4][4] = {};
  #pragma unroll
  for (int kk=0; kk<2; kk++){
    #pragma unroll
    for (int ni=0; ni<4; ni++){
      bf16x8 bsp = *(const bf16x8*)&SpT[ni*16 + lr][kk*32 + lg*8];
      #pragma unroll
      for (int mi=0; mi<4; mi++)
        accO[mi][ni] = MFMA16(af[mi][kk], bsp, accO[mi][ni]);
    }
  }
  f32x4 den4[4] = {};
  for (int t=0; t<4; ++t){
    __syncthreads();
    #pragma unroll
    for (int i=0; i<2; i++){
      int tau = tid + i*256;
      int m = tau & 63, dg = (tau >> 6) * 8;
      size_t g = ((size_t)(b*Ll + c*CHk + t*64 + m))*3072 + h*64 + dg;
      *(bf16x8*)&Ks[m][dg] = *(const bf16x8*)(qkv + g + 1024);
      bf16x8 vv = *(const bf16x8*)(qkv + g + 2048);
      #pragma unroll
      for (int u=0; u<8; u++) Vt[dg+u][m] = (unsigned short)vv[u];
    }
    __syncthreads();
    if (wave < t) continue;
    f32x4 sacc[4][4] = {};
    #pragma unroll
    for (int kk=0; kk<2; kk++){
      #pragma unroll
      for (int ni=0; ni<4; ni++){
        bf16x8 kf = *(const bf16x8*)&Ks[ni*16 + lr][kk*32 + lg*8];
        #pragma unroll
        for (int mi=0; mi<4; mi++)
          sacc[mi][ni] = MFMA16(af[mi][kk], kf, sacc[mi][ni]);
      }
    }
    unsigned short (*Pw)[72] = P[wave];
    bool diag = (t == wave);
    #pragma unroll
    for (int mi=0; mi<4; mi++){
      #pragma unroll
      for (int r=0; r<4; r++){
        int q_l = mi*16 + lg*4 + r;
        float rs = 0.f;
        #pragma unroll
        for (int ni=0; ni<4; ni++){
          int m_l = ni*16 + lr;
          float v = sacc[mi][ni][r];
          if (diag && m_l > q_l) v = 0.f;
          rs += v;
          Pw[q_l][m_l] = f2bf(v);
        }
        rs += __shfl_xor(rs, 1);
        rs += __shfl_xor(rs, 2);
        rs += __shfl_xor(rs, 4);
        rs += __shfl_xor(rs, 8);
        den4[mi][r] += rs;
      }
    }
    #pragma unroll
    for (int kk=0; kk<2; kk++){
      bf16x8 pa[4], vf[4];
      #pragma unroll
      for (int mi=0; mi<4; mi++) pa[mi] = *(const bf16x8*)&Pw[mi*16 + lr][kk*32 + lg*8];
      #pragma unroll
      for (int ni=0; ni<4; ni++) vf[ni] = *(const bf16x8*)&Vt[ni*16 + lr][kk*32 + lg*8];
      #pragma unroll
      for (int mi=0; mi<4; mi++)
        #pragma unroll
        for (int ni=0; ni<4; ni++)
          accO[mi][ni] = MFMA16(pa[mi], vf[ni], accO[mi][ni]);
    }
  }
  #pragma unroll
  for (int mi=0; mi<4; mi++){
    #pragma unroll
    for (int r=0; r<4; r++){
      int q_l = mi*16 + lg*4 + r;
      float dtot = den4[mi][r] + qZd[wave*64 + q_l];
      float inv = 1.f / fmaxf(dtot, 1e-6f);
      size_t l = (size_t)(b*Ll + c*CHk + wave*64 + q_l);
      unsigned short* op = attn + l*Ee + h*64 + lr;
      #pragma unroll
      for (int ni=0; ni<4; ni++)
        op[ni*16] = f2bf(accO[mi][ni][r] * inv);
    }
  }
}

// ---------------- column mean over L, deterministic 2-stage ----------------
__global__ __launch_bounds__(256) void colmean1_kernel(const unsigned short* __restrict__ h2,
    float* __restrict__ partial){
  int e = blockIdx.x*256 + threadIdx.x;
  int ly = blockIdx.y;
  int b = blockIdx.z;
  int l0 = ly * 128;
  float s = 0.f;
  for (int l=l0; l<l0+128; l++) s += bf2f(h2[((size_t)(b*Ll + l))*Ee + e]);
  partial[((size_t)(b*32 + ly))*Ee + e] = s;
}
__global__ __launch_bounds__(256) void colmean2_kernel(const float* __restrict__ partial,
    float* __restrict__ xmean){
  int e = blockIdx.x*256 + threadIdx.x;
  int b = blockIdx.y;
  float s = 0.f;
  #pragma unroll
  for (int ly=0; ly<32; ly++) s += partial[((size_t)(b*32 + ly))*Ee + e];
  xmean[b*Ee + e] = s * (1.f/Ll);
}

// ---------------- dim predictor -> floored size ----------------
__global__ __launch_bounds__(256) void dimpred_kernel(const float* __restrict__ xmean,
    const float* __restrict__ w_dp1, const float* __restrict__ w_dp2,
    float* __restrict__ scalars){
  __shared__ float red[256];
  __shared__ float ratio_s[2];
  int t = threadIdx.x;
  for (int b=0;b<2;b++){
    float s = 0.f;
    for (int k=0;k<1024;k++) s += xmean[b*Ee + k] * w_dp1[k*256 + t];
    float sil = s * (1.f/(1.f+expf(-s)));
    red[t] = sil * w_dp2[t];
    __syncthreads();
    for (int off=128; off>0; off>>=1){
      if (t<off) red[t] += red[t+off];
      __syncthreads();
    }
    if (t==0){
      float dr = 1.f/(1.f+expf(-red[0]));
      float ratio = 1.f + (dr-0.5f)*1.0f;       // 2*ADAPT = 1
      ratio = fminf(fmaxf(ratio, 0.5f), 1.5f);
      ratio_s[b] = ratio;
    }
    __syncthreads();
  }
  if (t==0){
    float rm = 0.5f*(ratio_s[0]+ratio_s[1]);
    float size_f = floorf(3072.f * rm);
    if (size_f < 1.f) size_f = 1.f;
    scalars[0] = size_f;
  }
}

extern "C" void kernel_launch(void* const* d_in, const int* in_sizes, int n_in,
                              void* d_out, int out_size, void* d_ws, size_t ws_size,
                              hipStream_t stream){
  const float* x      = (const float*)d_in[0];
  const float* w_qkv  = (const float*)d_in[1];
  const float* w_out  = (const float*)d_in[2];
  const float* g1     = (const float*)d_in[3];
  const float* g2     = (const float*)d_in[4];
  const float* w_dp1  = (const float*)d_in[5];
  const float* w_dp2  = (const float*)d_in[6];
  const float* w_gate = (const float*)d_in[7];
  const float* w_up   = (const float*)d_in[8];
  const float* w_down = (const float*)d_in[9];
  const float* g_hid  = (const float*)d_in[10];
  float* out = (float*)d_out;

  char* w = (char*)d_ws;
  size_t o = 0;
  auto alloc = [&](size_t bytes)->char*{ char* p = w + o; o += (bytes + 255) & ~255ull; return p; };
  unsigned short* R1   = (unsigned short*)alloc((size_t)8192*1024*2);   // h/attn/h2 bf16
  float*          x2   = (float*)alloc((size_t)8192*1024*4);            // post-attn residual fp32
  char*           R2   = alloc((size_t)8192*4608*2);                    // qkv bf16 then hidden
  unsigned short* qkvT = (unsigned short*)alloc((size_t)3072*1024*2);
  unsigned short* outT = (unsigned short*)alloc((size_t)1024*1024*2);
  char*           W2   = alloc((size_t)(9216+4608)*1024*2);             // Ssum/Spre then guT/downT
  float*       partial = (float*)alloc((size_t)64*1024*4);
  float*         xmean = (float*)alloc(2048*4);
  float*          scal = (float*)alloc(64);
  float*         sumsq = (float*)alloc(8192*4);

  unsigned short* qkv    = (unsigned short*)R2;
  unsigned short* hidden = (unsigned short*)R2;
  float* Ssum = (float*)W2;
  float* Spre = Ssum + (size_t)512*4160;
  unsigned short* guT   = (unsigned short*)W2;
  unsigned short* downT = guT + (size_t)9216*1024;

  wconv_kernel<<<dim3(3072/64, 1024/64),256,0,stream>>>(w_qkv, qkvT, 1024, 3072, nullptr, 0);
  wconv_kernel<<<dim3(1024/64, 1024/64),256,0,stream>>>(w_out, outT, 1024, 1024, nullptr, 0);

  rmsnorm_kernel<<<8192,256,0,stream>>>(x, g1, R1);
  gemm8p_kernel<<<dim3(3072/256, 8192/256),512,0,stream>>>(R1, qkvT, qkv, 8192,3072,1024);
  rope_kernel<<<16384,256,0,stream>>>(qkv);
  chunksum_kernel<<<dim3(NCc,Bb*Hh),256,0,stream>>>(qkv, Ssum);
  prefix_kernel<<<Bb*Hh,256,0,stream>>>(Ssum, Spre);
  attnout_kernel<<<dim3(NCc,Bb*Hh),256,0,stream>>>(qkv, Spre, R1);

  // Ssum/Spre dead now: convert FFN weights into W2
  wconv_kernel<<<dim3(4608/64, 1024/64),256,0,stream>>>(w_gate, guT, 1024, 4608, nullptr, 1);
  wconv_kernel<<<dim3(4608/64, 1024/64),256,0,stream>>>(w_up,   guT, 1024, 4608, nullptr, 2);
  wconv_kernel<<<dim3(1024/64, 4608/64),256,0,stream>>>(w_down, downT, 4608, 1024, g_hid, 0);

  gemm_kernel<1><<<dim3(1024/128, 8192/256),512,0,stream>>>(R1, outT, x2,
      8192,1024,1024, x,nullptr,nullptr);
  rmsnorm_kernel<<<8192,256,0,stream>>>(x2, g2, R1);
  colmean1_kernel<<<dim3(4,32,2),256,0,stream>>>(R1, partial);
  colmean2_kernel<<<dim3(4,2),256,0,stream>>>(partial, xmean);
  dimpred_kernel<<<1,256,0,stream>>>(xmean, w_dp1, w_dp2, scal);
  hipMemsetAsync(sumsq, 0, 8192*sizeof(float), stream);
  gateup8p_kernel<<<dim3(9216/256, 8192/256),512,0,stream>>>(R1, guT, hidden, scal, sumsq);
  gemm_kernel<2><<<dim3(1024/128, 8192/256),512,0,stream>>>(hidden, downT, out,
      8192,1024,4608, x2, sumsq, scal);
}

// Round 12
// 516.805 us; speedup vs baseline: 1.2288x; 1.2288x over previous
//
#include <hip/hip_runtime.h>
#include <hip/hip_bf16.h>

#define Ee 1024
#define Hh 16
#define Ff 4608
#define Ll 4096
#define Bb 2
#define NCc 16
#define CHk 256

typedef short bf16x8 __attribute__((ext_vector_type(8)));
typedef float f32x4 __attribute__((ext_vector_type(4)));

#define GLD16(g, l) __builtin_amdgcn_global_load_lds( \
    (const __attribute__((address_space(1))) unsigned int*)(g), \
    (__attribute__((address_space(3))) unsigned int*)(l), 16, 0, 0)
#define SCHED0() __builtin_amdgcn_sched_barrier(0)
#define SBAR()   __builtin_amdgcn_s_barrier()
#define MFMA16(a,b,c) __builtin_amdgcn_mfma_f32_16x16x32_bf16(a,b,c,0,0,0)

__device__ __forceinline__ unsigned short f2bf(float f){
  unsigned int u = __builtin_bit_cast(unsigned int, f);
  u += 0x7fffu + ((u >> 16) & 1u);
  return (unsigned short)(u >> 16);
}
__device__ __forceinline__ float bf2f(unsigned short h){
  unsigned int u = ((unsigned int)h) << 16;
  return __builtin_bit_cast(float, u);
}
__device__ __forceinline__ float fixv(float v){
  return (__builtin_isnan(v) || __builtin_isinf(v)) ? 0.f : v;
}

// ---------------- weight convert+transpose: W[K][N] fp32 -> WT[N][K] bf16 ----------------
__global__ __launch_bounds__(256) void wconv_kernel(const float* __restrict__ W,
    unsigned short* __restrict__ WT, int K, int N, const float* __restrict__ scale){
  __shared__ unsigned short T[64][72];
  int k0 = blockIdx.y*64, n0 = blockIdx.x*64;
  int t = threadIdx.x;
  int kr = t>>4, n4 = (t&15)*4;
  #pragma unroll
  for (int it=0; it<4; it++){
    int k = kr + it*16;
    float s = scale ? scale[k0+k] : 1.f;
    float4 v = *(const float4*)(W + (size_t)(k0+k)*N + n0 + n4);
    T[n4+0][k] = f2bf(v.x*s);
    T[n4+1][k] = f2bf(v.y*s);
    T[n4+2][k] = f2bf(v.z*s);
    T[n4+3][k] = f2bf(v.w*s);
  }
  __syncthreads();
  int u = t&7;
  #pragma unroll
  for (int it=0; it<2; it++){
    int n = (t>>3) + it*32;
    *(bf16x8*)(WT + (size_t)(n0+n)*K + k0 + u*8) = *(const bf16x8*)&T[n][u*8];
  }
}

// ---------------- RMSNorm fp32 in -> bf16 out ----------------
__global__ __launch_bounds__(256) void rmsnorm_kernel(const float* __restrict__ x,
    const float* __restrict__ g, unsigned short* __restrict__ out){
  int row = blockIdx.x; int t = threadIdx.x;
  float4 v = ((const float4*)(x + (size_t)row*Ee))[t];
  v.x=fixv(v.x); v.y=fixv(v.y); v.z=fixv(v.z); v.w=fixv(v.w);
  float ss = v.x*v.x + v.y*v.y + v.z*v.z + v.w*v.w;
  #pragma unroll
  for (int off=32; off>0; off>>=1) ss += __shfl_down(ss, off);
  __shared__ float red[4];
  if ((t&63)==0) red[t>>6] = ss;
  __syncthreads();
  float tot = red[0]+red[1]+red[2]+red[3];
  float rms = sqrtf(tot*(1.f/Ee) + 1e-6f);
  rms = fminf(fmaxf(rms, 1e-6f), 1e6f);
  float inv = 1.f/rms;
  float4 gv = ((const float4*)g)[t];
  uint2 o;
  o.x = (unsigned)f2bf(v.x*inv*gv.x) | ((unsigned)f2bf(v.y*inv*gv.y)<<16);
  o.y = (unsigned)f2bf(v.z*inv*gv.z) | ((unsigned)f2bf(v.w*inv*gv.w)<<16);
  ((uint2*)(out + (size_t)row*Ee))[t] = o;
}

// ---------------- bf16 GEMM: C[M,N] = A[M,K] @ Bt[N,K]^T ----------------
// 256x128 tile, 512 thr, BK=32, 3-buffer LDS rotation (72KB) with counted vmcnt.
// MODE 0: C bf16 with RoPE+ELU fused for cols<2048 (qkv only; N=3072, rows are b*4096+pos).
// MODE 1: C fp32 = acc + res.
// MODE 2: C fp32 = acc*inv_rms(sumsq[row], klim[0]) + res; K truncated to round32(klim[0]).
template<int MODE>
__global__ __launch_bounds__(512) void gemm_kernel(
    const unsigned short* __restrict__ A, const unsigned short* __restrict__ Bt,
    void* __restrict__ Cv, int M, int N, int K,
    const float* __restrict__ res, const float* __restrict__ rowscale,
    const float* __restrict__ klim){
  __shared__ __align__(16) unsigned short S[36864];   // 3 bufs x 12288 (A 8192 | B 4096)
  int tid = threadIdx.x;
  int nbx = gridDim.x;
  int id = blockIdx.y * nbx + blockIdx.x;
  int chunk = (nbx * gridDim.y) >> 3;
  int wg = (id & 7) * chunk + (id >> 3);
  int m0 = (wg / nbx) * 256, n0 = (wg % nbx) * 128;
  int lane = tid & 63, wave = tid >> 6;
  int wm = (wave>>1)*64, wn = (wave&1)*64;
  int lrow = lane & 15;
  int lksw = (((lane>>4) ^ ((lrow>>1)&3)))*8;
  float klim0 = (MODE==2 && klim) ? klim[0] : 0.f;
  int kend = K;
  if (MODE==2 && klim){
    int sz = (int)klim0;
    int ke = ((sz + 31) >> 5) << 5;
    kend = ke < K ? ke : K;
  }
  int nk = kend >> 5;
  int segr = lane >> 2;
  int cg = (((lane&3) ^ ((lane>>3)&3))) * 8;
  const unsigned short* gp[3];
  int loff[3];
  #pragma unroll
  for (int i=0;i<3;i++){
    int g = wave*3 + i;
    if (g < 16){ gp[i] = A  + (size_t)(m0 + g*16 + segr)*K + cg;       loff[i] = g*512; }
    else       { gp[i] = Bt + (size_t)(n0 + (g-16)*16 + segr)*K + cg;  loff[i] = 8192 + (g-16)*512; }
  }
  f32x4 acc[4][4] = {};
  #pragma unroll
  for (int i=0;i<3;i++) GLD16(gp[i], &S[loff[i]]);
  if (nk > 1){
    #pragma unroll
    for (int i=0;i<3;i++) GLD16(gp[i]+32, &S[12288 + loff[i]]);
  }
  SCHED0();
  if (nk > 1) asm volatile("s_waitcnt vmcnt(3)" ::: "memory");
  else        asm volatile("s_waitcnt vmcnt(0)" ::: "memory");
  SBAR(); SCHED0();
  int cur = 0;
  for (int t=0; t<nk; ++t){
    if (t+2 < nk){
      int stg = cur+2; if (stg>=3) stg-=3;
      int ko = (t+2) << 5;
      #pragma unroll
      for (int i=0;i<3;i++) GLD16(gp[i]+ko, &S[stg*12288 + loff[i]]);
    }
    int base = cur*12288;
    bf16x8 af[4], bfr[4];
    #pragma unroll
    for (int i=0;i<4;i++){
      af[i]  = *(const bf16x8*)&S[base + (wm + i*16 + lrow)*32 + lksw];
      bfr[i] = *(const bf16x8*)&S[base + 8192 + (wn + i*16 + lrow)*32 + lksw];
    }
    __builtin_amdgcn_s_setprio(1);
    #pragma unroll
    for (int mi=0;mi<4;mi++)
      #pragma unroll
      for (int ni=0;ni<4;ni++)
        acc[mi][ni] = MFMA16(af[mi], bfr[ni], acc[mi][ni]);
    __builtin_amdgcn_s_setprio(0);
    if (t+1 < nk){
      SCHED0();
      if (t+2 < nk) asm volatile("s_waitcnt vmcnt(3)" ::: "memory");
      else          asm volatile("s_waitcnt vmcnt(0)" ::: "memory");
      SBAR(); SCHED0();
    }
    cur = (cur==2) ? 0 : cur+1;
  }
  int lg = lane >> 4;
  int rbase = m0 + wm + (lg<<2);
  int cbase = n0 + wn + lrow;
  // MODE 0 rope setup: within a wave, cols span one 64-aligned window -> one section/head.
  bool do_rope = false;
  float fb[4];
  if (MODE==0){
    do_rope = (cbase < 2048);     // q or k section
    if (do_rope){
      const float LOG1E4_D32 = 0.2878231366242557f;  // ln(10000)/32
      float e0 = (float)lrow;                         // d = lrow + ni*16
      float e1 = (float)(lrow + 16);
      fb[0] = expf(-e0*LOG1E4_D32);  // ni=0: d=lrow      (e=lrow)
      fb[1] = expf(-e1*LOG1E4_D32);  // ni=1: d=lrow+16   (e=lrow+16)
      fb[2] = fb[0];                 // ni=2: d=lrow+32   (e=lrow)
      fb[3] = fb[1];                 // ni=3: d=lrow+48   (e=lrow+16)
    }
  }
  #pragma unroll
  for (int mi=0;mi<4;mi++){
    #pragma unroll
    for (int r=0;r<4;r++){
      int row = rbase + mi*16 + r;
      float rs = 1.f;
      if (MODE==2){
        float rms = sqrtf(rowscale[row]/klim0 + 1e-6f);
        rms = fminf(fmaxf(rms, 1e-6f), 1e6f);
        rs = 1.f/rms;
      }
      float pos = (float)(row & (Ll-1));
      #pragma unroll
      for (int ni=0;ni<4;ni++){
        int col = cbase + ni*16;
        float v = acc[mi][ni][r];
        if (MODE==0){
          float o = v;
          if (do_rope){
            float p = __shfl_xor(v, 1);        // pair element (adjacent col)
            float f = pos * fb[ni];
            float s, cft;
            __sincosf(f, &s, &cft);
            // even d: o = v*c - p*s ; odd d: o = v*c + p*s
            o = (lrow & 1) ? (v*cft + p*s) : (v*cft - p*s);
            o = o > 0.f ? o + 1.f : expf(o);   // elu(x)+1
          }
          ((unsigned short*)Cv)[(size_t)row*N + col] = f2bf(o);
        } else if (MODE==1){
          ((float*)Cv)[(size_t)row*N + col] = v + res[(size_t)row*N + col];
        } else {
          ((float*)Cv)[(size_t)row*N + col] = v*rs + res[(size_t)row*N + col];
        }
      }
    }
  }
}

// ---------------- fused gate+up GEMM (256x128, BK=32, 2-buffer, 64KB LDS) ----------------
// hidden = silu(g)*u masked; accumulates per-row sumsq (fp32 atomics).  [r8 structure: best measured]
__global__ __launch_bounds__(512) void gateup_kernel(
    const unsigned short* __restrict__ A, const unsigned short* __restrict__ Gt,
    const unsigned short* __restrict__ Ut, unsigned short* __restrict__ Hid,
    const float* __restrict__ scal, float* __restrict__ sumsq){
  __shared__ __align__(16) unsigned short S[2][16384];  // A[0,8192) G[8192,12288) U[12288,16384)
  int tid = threadIdx.x;
  int nbx = gridDim.x;
  int id = blockIdx.y * nbx + blockIdx.x;
  int chunk = (nbx * gridDim.y) >> 3;
  int wg = (id & 7) * chunk + (id >> 3);
  int m0 = (wg / nbx) * 256, n0 = (wg % nbx) * 128;
  int size = (int)scal[0];
  if (n0 >= size){
    int r = tid >> 1, cb = n0 + (tid&1)*64;
    unsigned short* hp = Hid + (size_t)(m0+r)*Ff + cb;
    bf16x8 z = {};
    #pragma unroll
    for (int i=0;i<8;i++) *(bf16x8*)(hp + i*8) = z;
    return;
  }
  int lane = tid & 63, wave = tid >> 6;
  int wm = (wave>>1)*64, wn = (wave&1)*64;
  int lrow = lane & 15;
  int lksw = (((lane>>4) ^ ((lrow>>1)&3)))*8;
  int segr = lane >> 2;
  int cg = (((lane&3) ^ ((lane>>3)&3))) * 8;
  const unsigned short* gp[4];
  int loff[4];
  #pragma unroll
  for (int i=0;i<4;i++){
    int g = wave*4 + i;
    if (g < 16)      { gp[i] = A  + (size_t)(m0 + g*16 + segr)*Ee + cg;       loff[i] = g*512; }
    else if (g < 24) { gp[i] = Gt + (size_t)(n0 + (g-16)*16 + segr)*Ee + cg;  loff[i] = 8192 + (g-16)*512; }
    else             { gp[i] = Ut + (size_t)(n0 + (g-24)*16 + segr)*Ee + cg;  loff[i] = 12288 + (g-24)*512; }
  }
  f32x4 ag[4][4] = {}, au[4][4] = {};
  #pragma unroll
  for (int i=0;i<4;i++) GLD16(gp[i], &S[0][loff[i]]);
  __syncthreads();
  int cur = 0;
  for (int t=0; t<32; ++t){
    if (t+1 < 32){
      int ko = (t+1) << 5;
      #pragma unroll
      for (int i=0;i<4;i++) GLD16(gp[i]+ko, &S[cur^1][loff[i]]);
    }
    bf16x8 af[4], bg4[4], bu4[4];
    #pragma unroll
    for (int i=0;i<4;i++){
      af[i]  = *(const bf16x8*)&S[cur][(wm + i*16 + lrow)*32 + lksw];
      bg4[i] = *(const bf16x8*)&S[cur][8192  + (wn + i*16 + lrow)*32 + lksw];
      bu4[i] = *(const bf16x8*)&S[cur][12288 + (wn + i*16 + lrow)*32 + lksw];
    }
    __builtin_amdgcn_s_setprio(1);
    #pragma unroll
    for (int mi=0;mi<4;mi++)
      #pragma unroll
      for (int ni=0;ni<4;ni++){
        ag[mi][ni] = MFMA16(af[mi], bg4[ni], ag[mi][ni]);
        au[mi][ni] = MFMA16(af[mi], bu4[ni], au[mi][ni]);
      }
    __builtin_amdgcn_s_setprio(0);
    __syncthreads();
    cur ^= 1;
  }
  int lg = lane >> 4;
  int lr = lrow;
  int rbase = m0 + wm + (lg<<2);
  int cbase = n0 + wn + lr;
  #pragma unroll
  for (int mi=0;mi<4;mi++){
    #pragma unroll
    for (int r=0;r<4;r++){
      int row = rbase + mi*16 + r;
      float s4 = 0.f;
      #pragma unroll
      for (int ni=0;ni<4;ni++){
        int col = cbase + ni*16;
        float g = ag[mi][ni][r], u = au[mi][ni][r];
        float hv = (g * (1.f/(1.f+expf(-g)))) * u;
        if (col >= size) hv = 0.f;
        if (__builtin_isnan(hv) || __builtin_isinf(hv)) hv = 0.f;
        Hid[(size_t)row*Ff + col] = f2bf(hv);
        s4 += hv*hv;
      }
      s4 += __shfl_xor(s4, 1);
      s4 += __shfl_xor(s4, 2);
      s4 += __shfl_xor(s4, 4);
      s4 += __shfl_xor(s4, 8);
      if (lr == 0) atomicAdd(&sumsq[row], s4);
    }
  }
}

// ---------------- per-chunk K^T V + K col sums via MFMA (ones-column trick) ----------------
__global__ __launch_bounds__(256) void chunksum_kernel(const unsigned short* __restrict__ qkv,
    float* __restrict__ Ssum){
  __shared__ __align__(16) unsigned short Kt[64][72];   // K^T[j][m]
  __shared__ __align__(16) unsigned short Vt[80][72];   // V^T[e][m]; row64=1.0, 65..79=0
  int c = blockIdx.x, bh = blockIdx.y;
  int b = bh >> 4, h = bh & 15;
  int tid = threadIdx.x, lane = tid & 63, wave = tid >> 6;
  int lr = lane & 15, lg = lane >> 4;
  f32x4 acc[5] = {};
  {
    int r16 = tid >> 4, m4 = (tid & 15) * 4;
    unsigned short val = (r16 == 0) ? (unsigned short)0x3F80 : (unsigned short)0;
    #pragma unroll
    for (int u=0; u<4; u++) Vt[64 + r16][m4 + u] = val;
  }
  for (int t=0; t<4; ++t){
    __syncthreads();
    #pragma unroll
    for (int i=0; i<2; i++){
      int tau = tid + i*256;
      int m = tau & 63, dg = (tau >> 6) * 8;
      size_t g = ((size_t)(b*Ll + c*CHk + t*64 + m))*3072 + h*64 + dg;
      bf16x8 kv = *(const bf16x8*)(qkv + g + 1024);
      bf16x8 vv = *(const bf16x8*)(qkv + g + 2048);
      #pragma unroll
      for (int u=0; u<8; u++){
        Kt[dg+u][m] = (unsigned short)kv[u];
        Vt[dg+u][m] = (unsigned short)vv[u];
      }
    }
    __syncthreads();
    #pragma unroll
    for (int kk=0; kk<2; kk++){
      bf16x8 af = *(const bf16x8*)&Kt[wave*16 + lr][kk*32 + lg*8];
      #pragma unroll
      for (int ni=0; ni<5; ni++){
        bf16x8 vf = *(const bf16x8*)&Vt[ni*16 + lr][kk*32 + lg*8];
        acc[ni] = MFMA16(af, vf, acc[ni]);
      }
    }
  }
  float* S = Ssum + ((size_t)bh*NCc + c)*4160;
  int j = wave*16 + lg*4;
  #pragma unroll
  for (int ni=0; ni<4; ni++)
    #pragma unroll
    for (int r=0; r<4; r++)
      S[(size_t)(j+r)*64 + ni*16 + lr] = acc[ni][r];
  if (lr == 0){
    #pragma unroll
    for (int r=0; r<4; r++) S[4096 + j + r] = acc[4][r];
  }
}

// ---------------- exclusive prefix over chunks ----------------
__global__ __launch_bounds__(256) void prefix_kernel(const float* __restrict__ Ssum,
    float* __restrict__ Spre){
  int bh = blockIdx.x; int t = threadIdx.x;
  size_t base = (size_t)bh*NCc*4160;
  for (int e=t; e<4160; e+=256){
    float acc = 0.f;
    #pragma unroll
    for (int c=0;c<NCc;c++){
      Spre[base + (size_t)c*4160 + e] = acc;
      acc += Ssum[base + (size_t)c*4160 + e];
    }
  }
}

// ---------------- per-chunk causal attention via MFMA ----------------
__global__ __launch_bounds__(256, 2) void attnout_kernel(const unsigned short* __restrict__ qkv,
    const float* __restrict__ Spre, unsigned short* __restrict__ attn){
  __shared__ __align__(16) unsigned short SpT[64][72];     // Spre^T[e][j] bf16
  __shared__ __align__(16) unsigned short Ks[64][72];      // K[m][d]
  __shared__ __align__(16) unsigned short Vt[64][72];      // V^T[d][m]
  __shared__ __align__(16) unsigned short P[4][64][72];    // per-wave masked S bf16
  __shared__ float qZd[256];
  int c = blockIdx.x, bh = blockIdx.y;
  int b = bh >> 4, h = bh & 15;
  int tid = threadIdx.x, lane = tid & 63, wave = tid >> 6;
  int lr = lane & 15, lg = lane >> 4;
  const float* Sp = Spre + ((size_t)bh*NCc + c)*4160;

  {
    float zacc = 0.f;
    const unsigned short* qp = qkv + ((size_t)(b*Ll + c*CHk + tid))*3072 + (size_t)h*64;
    #pragma unroll
    for (int g8=0; g8<8; g8++){
      bf16x8 qv = *(const bf16x8*)(qp + g8*8);
      #pragma unroll
      for (int u=0; u<8; u++) zacc += bf2f((unsigned short)qv[u]) * Sp[4096 + g8*8 + u];
    }
    qZd[tid] = zacc;
  }
  #pragma unroll
  for (int i=0; i<2; i++){
    int tau = tid + i*256;
    int j = tau & 63, dg = (tau >> 6) * 8;
    const float* sp = Sp + j*64 + dg;
    #pragma unroll
    for (int u=0; u<8; u++) SpT[dg+u][j] = f2bf(sp[u]);
  }
  bf16x8 af[4][2];
  #pragma unroll
  for (int mi=0; mi<4; mi++){
    size_t qrow = ((size_t)(b*Ll + c*CHk + wave*64 + mi*16 + lr))*3072 + (size_t)h*64;
    #pragma unroll
    for (int kk=0; kk<2; kk++)
      af[mi][kk] = *(const bf16x8*)(qkv + qrow + kk*32 + lg*8);
  }
  __syncthreads();
  f32x4 accO[4][4] = {};
  #pragma unroll
  for (int kk=0; kk<2; kk++){
    #pragma unroll
    for (int ni=0; ni<4; ni++){
      bf16x8 bsp = *(const bf16x8*)&SpT[ni*16 + lr][kk*32 + lg*8];
      #pragma unroll
      for (int mi=0; mi<4; mi++)
        accO[mi][ni] = MFMA16(af[mi][kk], bsp, accO[mi][ni]);
    }
  }
  f32x4 den4[4] = {};
  for (int t=0; t<4; ++t){
    __syncthreads();
    #pragma unroll
    for (int i=0; i<2; i++){
      int tau = tid + i*256;
      int m = tau & 63, dg = (tau >> 6) * 8;
      size_t g = ((size_t)(b*Ll + c*CHk + t*64 + m))*3072 + h*64 + dg;
      *(bf16x8*)&Ks[m][dg] = *(const bf16x8*)(qkv + g + 1024);
      bf16x8 vv = *(const bf16x8*)(qkv + g + 2048);
      #pragma unroll
      for (int u=0; u<8; u++) Vt[dg+u][m] = (unsigned short)vv[u];
    }
    __syncthreads();
    if (wave < t) continue;
    f32x4 sacc[4][4] = {};
    #pragma unroll
    for (int kk=0; kk<2; kk++){
      #pragma unroll
      for (int ni=0; ni<4; ni++){
        bf16x8 kf = *(const bf16x8*)&Ks[ni*16 + lr][kk*32 + lg*8];
        #pragma unroll
        for (int mi=0; mi<4; mi++)
          sacc[mi][ni] = MFMA16(af[mi][kk], kf, sacc[mi][ni]);
      }
    }
    unsigned short (*Pw)[72] = P[wave];
    bool diag = (t == wave);
    #pragma unroll
    for (int mi=0; mi<4; mi++){
      #pragma unroll
      for (int r=0; r<4; r++){
        int q_l = mi*16 + lg*4 + r;
        float rs = 0.f;
        #pragma unroll
        for (int ni=0; ni<4; ni++){
          int m_l = ni*16 + lr;
          float v = sacc[mi][ni][r];
          if (diag && m_l > q_l) v = 0.f;
          rs += v;
          Pw[q_l][m_l] = f2bf(v);
        }
        rs += __shfl_xor(rs, 1);
        rs += __shfl_xor(rs, 2);
        rs += __shfl_xor(rs, 4);
        rs += __shfl_xor(rs, 8);
        den4[mi][r] += rs;
      }
    }
    #pragma unroll
    for (int kk=0; kk<2; kk++){
      bf16x8 pa[4], vf[4];
      #pragma unroll
      for (int mi=0; mi<4; mi++) pa[mi] = *(const bf16x8*)&Pw[mi*16 + lr][kk*32 + lg*8];
      #pragma unroll
      for (int ni=0; ni<4; ni++) vf[ni] = *(const bf16x8*)&Vt[ni*16 + lr][kk*32 + lg*8];
      #pragma unroll
      for (int mi=0; mi<4; mi++)
        #pragma unroll
        for (int ni=0; ni<4; ni++)
          accO[mi][ni] = MFMA16(pa[mi], vf[ni], accO[mi][ni]);
    }
  }
  #pragma unroll
  for (int mi=0; mi<4; mi++){
    #pragma unroll
    for (int r=0; r<4; r++){
      int q_l = mi*16 + lg*4 + r;
      float dtot = den4[mi][r] + qZd[wave*64 + q_l];
      float inv = 1.f / fmaxf(dtot, 1e-6f);
      size_t l = (size_t)(b*Ll + c*CHk + wave*64 + q_l);
      unsigned short* op = attn + l*Ee + h*64 + lr;
      #pragma unroll
      for (int ni=0; ni<4; ni++)
        op[ni*16] = f2bf(accO[mi][ni][r] * inv);
    }
  }
}

// ---------------- column mean over L, deterministic 2-stage ----------------
__global__ __launch_bounds__(256) void colmean1_kernel(const unsigned short* __restrict__ h2,
    float* __restrict__ partial){
  int e = blockIdx.x*256 + threadIdx.x;
  int ly = blockIdx.y;
  int b = blockIdx.z;
  int l0 = ly * 128;
  float s = 0.f;
  for (int l=l0; l<l0+128; l++) s += bf2f(h2[((size_t)(b*Ll + l))*Ee + e]);
  partial[((size_t)(b*32 + ly))*Ee + e] = s;
}
__global__ __launch_bounds__(256) void colmean2_kernel(const float* __restrict__ partial,
    float* __restrict__ xmean){
  int e = blockIdx.x*256 + threadIdx.x;
  int b = blockIdx.y;
  float s = 0.f;
  #pragma unroll
  for (int ly=0; ly<32; ly++) s += partial[((size_t)(b*32 + ly))*Ee + e];
  xmean[b*Ee + e] = s * (1.f/Ll);
}

// ---------------- dim predictor -> floored size ----------------
__global__ __launch_bounds__(256) void dimpred_kernel(const float* __restrict__ xmean,
    const float* __restrict__ w_dp1, const float* __restrict__ w_dp2,
    float* __restrict__ scalars){
  __shared__ float red[256];
  __shared__ float ratio_s[2];
  int t = threadIdx.x;
  for (int b=0;b<2;b++){
    float s = 0.f;
    for (int k=0;k<1024;k++) s += xmean[b*Ee + k] * w_dp1[k*256 + t];
    float sil = s * (1.f/(1.f+expf(-s)));
    red[t] = sil * w_dp2[t];
    __syncthreads();
    for (int off=128; off>0; off>>=1){
      if (t<off) red[t] += red[t+off];
      __syncthreads();
    }
    if (t==0){
      float dr = 1.f/(1.f+expf(-red[0]));
      float ratio = 1.f + (dr-0.5f)*1.0f;       // 2*ADAPT = 1
      ratio = fminf(fmaxf(ratio, 0.5f), 1.5f);
      ratio_s[b] = ratio;
    }
    __syncthreads();
  }
  if (t==0){
    float rm = 0.5f*(ratio_s[0]+ratio_s[1]);
    float size_f = floorf(3072.f * rm);
    if (size_f < 1.f) size_f = 1.f;
    scalars[0] = size_f;
  }
}

extern "C" void kernel_launch(void* const* d_in, const int* in_sizes, int n_in,
                              void* d_out, int out_size, void* d_ws, size_t ws_size,
                              hipStream_t stream){
  const float* x      = (const float*)d_in[0];
  const float* w_qkv  = (const float*)d_in[1];
  const float* w_out  = (const float*)d_in[2];
  const float* g1     = (const float*)d_in[3];
  const float* g2     = (const float*)d_in[4];
  const float* w_dp1  = (const float*)d_in[5];
  const float* w_dp2  = (const float*)d_in[6];
  const float* w_gate = (const float*)d_in[7];
  const float* w_up   = (const float*)d_in[8];
  const float* w_down = (const float*)d_in[9];
  const float* g_hid  = (const float*)d_in[10];
  float* out = (float*)d_out;

  char* w = (char*)d_ws;
  size_t o = 0;
  auto alloc = [&](size_t bytes)->char*{ char* p = w + o; o += (bytes + 255) & ~255ull; return p; };
  unsigned short* R1   = (unsigned short*)alloc((size_t)8192*1024*2);   // h/attn/h2 bf16
  float*          x2   = (float*)alloc((size_t)8192*1024*4);            // post-attn residual fp32
  char*           R2   = alloc((size_t)8192*4608*2);                    // qkv bf16 then hidden
  unsigned short* qkvT = (unsigned short*)alloc((size_t)3072*1024*2);
  unsigned short* outT = (unsigned short*)alloc((size_t)1024*1024*2);
  char*           W2   = alloc((size_t)3*4608*1024*2);                  // Ssum/Spre then gateT/upT/downT
  float*       partial = (float*)alloc((size_t)64*1024*4);
  float*         xmean = (float*)alloc(2048*4);
  float*          scal = (float*)alloc(64);
  float*         sumsq = (float*)alloc(8192*4);

  unsigned short* qkv    = (unsigned short*)R2;
  unsigned short* hidden = (unsigned short*)R2;
  float* Ssum = (float*)W2;
  float* Spre = Ssum + (size_t)512*4160;
  unsigned short* gateT = (unsigned short*)W2;
  unsigned short* upT   = gateT + (size_t)4608*1024;
  unsigned short* downT = upT   + (size_t)4608*1024;

  wconv_kernel<<<dim3(3072/64, 1024/64),256,0,stream>>>(w_qkv, qkvT, 1024, 3072, nullptr);
  wconv_kernel<<<dim3(1024/64, 1024/64),256,0,stream>>>(w_out, outT, 1024, 1024, nullptr);

  rmsnorm_kernel<<<8192,256,0,stream>>>(x, g1, R1);
  gemm_kernel<0><<<dim3(3072/128, 8192/256),512,0,stream>>>(R1, qkvT, qkv,
      8192,3072,1024, nullptr,nullptr,nullptr);      // rope+elu fused in epilogue
  chunksum_kernel<<<dim3(NCc,Bb*Hh),256,0,stream>>>(qkv, Ssum);
  prefix_kernel<<<Bb*Hh,256,0,stream>>>(Ssum, Spre);
  attnout_kernel<<<dim3(NCc,Bb*Hh),256,0,stream>>>(qkv, Spre, R1);

  wconv_kernel<<<dim3(4608/64, 1024/64),256,0,stream>>>(w_gate, gateT, 1024, 4608, nullptr);
  wconv_kernel<<<dim3(4608/64, 1024/64),256,0,stream>>>(w_up,   upT,   1024, 4608, nullptr);
  wconv_kernel<<<dim3(1024/64, 4608/64),256,0,stream>>>(w_down, downT, 4608, 1024, g_hid);

  gemm_kernel<1><<<dim3(1024/128, 8192/256),512,0,stream>>>(R1, outT, x2,
      8192,1024,1024, x,nullptr,nullptr);
  rmsnorm_kernel<<<8192,256,0,stream>>>(x2, g2, R1);
  colmean1_kernel<<<dim3(4,32,2),256,0,stream>>>(R1, partial);
  colmean2_kernel<<<dim3(4,2),256,0,stream>>>(partial, xmean);
  dimpred_kernel<<<1,256,0,stream>>>(xmean, w_dp1, w_dp2, scal);
  hipMemsetAsync(sumsq, 0, 8192*sizeof(float), stream);
  gateup_kernel<<<dim3(4608/128, 8192/256),512,0,stream>>>(R1, gateT, upT, hidden, scal, sumsq);
  gemm_kernel<2><<<dim3(1024/128, 8192/256),512,0,stream>>>(hidden, downT, out,
      8192,1024,4608, x2, sumsq, scal);
}

// Round 13
// 475.353 us; speedup vs baseline: 1.3359x; 1.0872x over previous
//
#include <hip/hip_runtime.h>
#include <hip/hip_bf16.h>

#define Ee 1024
#define Hh 16
#define Ff 4608
#define Ll 4096
#define Bb 2
#define NCc 16
#define CHk 256

typedef short bf16x8 __attribute__((ext_vector_type(8)));
typedef float f32x4 __attribute__((ext_vector_type(4)));

#define GLD16(g, l) __builtin_amdgcn_global_load_lds( \
    (const __attribute__((address_space(1))) unsigned int*)(g), \
    (__attribute__((address_space(3))) unsigned int*)(l), 16, 0, 0)
#define SCHED0() __builtin_amdgcn_sched_barrier(0)
#define SBAR()   __builtin_amdgcn_s_barrier()
#define MFMA16(a,b,c) __builtin_amdgcn_mfma_f32_16x16x32_bf16(a,b,c,0,0,0)

__device__ __forceinline__ unsigned short f2bf(float f){
  unsigned int u = __builtin_bit_cast(unsigned int, f);
  u += 0x7fffu + ((u >> 16) & 1u);
  return (unsigned short)(u >> 16);
}
__device__ __forceinline__ float bf2f(unsigned short h){
  unsigned int u = ((unsigned int)h) << 16;
  return __builtin_bit_cast(float, u);
}
__device__ __forceinline__ float fixv(float v){
  return (__builtin_isnan(v) || __builtin_isinf(v)) ? 0.f : v;
}

// ---------------- weight convert+transpose: W[K][N] fp32 -> WT[N][K] bf16 ----------------
__global__ __launch_bounds__(256) void wconv_kernel(const float* __restrict__ W,
    unsigned short* __restrict__ WT, int K, int N, const float* __restrict__ scale){
  __shared__ unsigned short T[64][72];
  int k0 = blockIdx.y*64, n0 = blockIdx.x*64;
  int t = threadIdx.x;
  int kr = t>>4, n4 = (t&15)*4;
  #pragma unroll
  for (int it=0; it<4; it++){
    int k = kr + it*16;
    float s = scale ? scale[k0+k] : 1.f;
    float4 v = *(const float4*)(W + (size_t)(k0+k)*N + n0 + n4);
    T[n4+0][k] = f2bf(v.x*s);
    T[n4+1][k] = f2bf(v.y*s);
    T[n4+2][k] = f2bf(v.z*s);
    T[n4+3][k] = f2bf(v.w*s);
  }
  __syncthreads();
  int u = t&7;
  #pragma unroll
  for (int it=0; it<2; it++){
    int n = (t>>3) + it*32;
    *(bf16x8*)(WT + (size_t)(n0+n)*K + k0 + u*8) = *(const bf16x8*)&T[n][u*8];
  }
}

// ---------------- RMSNorm fp32 in -> bf16 out ----------------
__global__ __launch_bounds__(256) void rmsnorm_kernel(const float* __restrict__ x,
    const float* __restrict__ g, unsigned short* __restrict__ out){
  int row = blockIdx.x; int t = threadIdx.x;
  float4 v = ((const float4*)(x + (size_t)row*Ee))[t];
  v.x=fixv(v.x); v.y=fixv(v.y); v.z=fixv(v.z); v.w=fixv(v.w);
  float ss = v.x*v.x + v.y*v.y + v.z*v.z + v.w*v.w;
  #pragma unroll
  for (int off=32; off>0; off>>=1) ss += __shfl_down(ss, off);
  __shared__ float red[4];
  if ((t&63)==0) red[t>>6] = ss;
  __syncthreads();
  float tot = red[0]+red[1]+red[2]+red[3];
  float rms = sqrtf(tot*(1.f/Ee) + 1e-6f);
  rms = fminf(fmaxf(rms, 1e-6f), 1e6f);
  float inv = 1.f/rms;
  float4 gv = ((const float4*)g)[t];
  uint2 o;
  o.x = (unsigned)f2bf(v.x*inv*gv.x) | ((unsigned)f2bf(v.y*inv*gv.y)<<16);
  o.y = (unsigned)f2bf(v.z*inv*gv.z) | ((unsigned)f2bf(v.w*inv*gv.w)<<16);
  ((uint2*)(out + (size_t)row*Ee))[t] = o;
}

// ---------------- RMSNorm bf16 in -> bf16 out ----------------
__global__ __launch_bounds__(256) void rmsnorm_b_kernel(const unsigned short* __restrict__ x,
    const float* __restrict__ g, unsigned short* __restrict__ out){
  int row = blockIdx.x; int t = threadIdx.x;
  uint2 raw = ((const uint2*)(x + (size_t)row*Ee))[t];
  float v0 = fixv(bf2f((unsigned short)(raw.x & 0xffff)));
  float v1 = fixv(bf2f((unsigned short)(raw.x >> 16)));
  float v2 = fixv(bf2f((unsigned short)(raw.y & 0xffff)));
  float v3 = fixv(bf2f((unsigned short)(raw.y >> 16)));
  float ss = v0*v0 + v1*v1 + v2*v2 + v3*v3;
  #pragma unroll
  for (int off=32; off>0; off>>=1) ss += __shfl_down(ss, off);
  __shared__ float red[4];
  if ((t&63)==0) red[t>>6] = ss;
  __syncthreads();
  float tot = red[0]+red[1]+red[2]+red[3];
  float rms = sqrtf(tot*(1.f/Ee) + 1e-6f);
  rms = fminf(fmaxf(rms, 1e-6f), 1e6f);
  float inv = 1.f/rms;
  float4 gv = ((const float4*)g)[t];
  uint2 o;
  o.x = (unsigned)f2bf(v0*inv*gv.x) | ((unsigned)f2bf(v1*inv*gv.y)<<16);
  o.y = (unsigned)f2bf(v2*inv*gv.z) | ((unsigned)f2bf(v3*inv*gv.w)<<16);
  ((uint2*)(out + (size_t)row*Ee))[t] = o;
}

// ---------------- bf16 GEMM: C[M,N] = A[M,K] @ Bt[N,K]^T ----------------
// 256x128 tile, 512 thr, BK=32, 3-buffer LDS rotation (72KB), counted vmcnt.
// MODE 0: C bf16, no residual (qkv).
// MODE 1: C bf16 = acc + res(fp32)   (out-proj; x2 stored bf16).
// MODE 2: C fp32 = acc*inv_rms(sumsq[row],klim[0]) + res(bf16); K trunc to round32(klim[0]).
template<int MODE>
__global__ __launch_bounds__(512) void gemm_kernel(
    const unsigned short* __restrict__ A, const unsigned short* __restrict__ Bt,
    void* __restrict__ Cv, int M, int N, int K,
    const void* __restrict__ resv, const float* __restrict__ rowscale,
    const float* __restrict__ klim){
  __shared__ __align__(16) unsigned short S[36864];   // 3 bufs x 12288 (A 8192 | B 4096)
  int tid = threadIdx.x;
  int nbx = gridDim.x;
  int id = blockIdx.y * nbx + blockIdx.x;
  int chunk = (nbx * gridDim.y) >> 3;
  int wg = (id & 7) * chunk + (id >> 3);
  int m0 = (wg / nbx) * 256, n0 = (wg % nbx) * 128;
  int lane = tid & 63, wave = tid >> 6;
  int wm = (wave>>1)*64, wn = (wave&1)*64;
  int lrow = lane & 15;
  int lksw = (((lane>>4) ^ ((lrow>>1)&3)))*8;
  float klim0 = (MODE==2 && klim) ? klim[0] : 0.f;
  int kend = K;
  if (MODE==2 && klim){
    int sz = (int)klim0;
    int ke = ((sz + 31) >> 5) << 5;
    kend = ke < K ? ke : K;
  }
  int nk = kend >> 5;
  int segr = lane >> 2;
  int cg = (((lane&3) ^ ((lane>>3)&3))) * 8;
  const unsigned short* gp[3];
  int loff[3];
  #pragma unroll
  for (int i=0;i<3;i++){
    int g = wave*3 + i;
    if (g < 16){ gp[i] = A  + (size_t)(m0 + g*16 + segr)*K + cg;       loff[i] = g*512; }
    else       { gp[i] = Bt + (size_t)(n0 + (g-16)*16 + segr)*K + cg;  loff[i] = 8192 + (g-16)*512; }
  }
  f32x4 acc[4][4] = {};
  #pragma unroll
  for (int i=0;i<3;i++) GLD16(gp[i], &S[loff[i]]);
  if (nk > 1){
    #pragma unroll
    for (int i=0;i<3;i++) GLD16(gp[i]+32, &S[12288 + loff[i]]);
  }
  SCHED0();
  if (nk > 1) asm volatile("s_waitcnt vmcnt(3)" ::: "memory");
  else        asm volatile("s_waitcnt vmcnt(0)" ::: "memory");
  SBAR(); SCHED0();
  int cur = 0;
  for (int t=0; t<nk; ++t){
    if (t+2 < nk){
      int stg = cur+2; if (stg>=3) stg-=3;
      int ko = (t+2) << 5;
      #pragma unroll
      for (int i=0;i<3;i++) GLD16(gp[i]+ko, &S[stg*12288 + loff[i]]);
    }
    int base = cur*12288;
    bf16x8 af[4], bfr[4];
    #pragma unroll
    for (int i=0;i<4;i++){
      af[i]  = *(const bf16x8*)&S[base + (wm + i*16 + lrow)*32 + lksw];
      bfr[i] = *(const bf16x8*)&S[base + 8192 + (wn + i*16 + lrow)*32 + lksw];
    }
    __builtin_amdgcn_s_setprio(1);
    #pragma unroll
    for (int mi=0;mi<4;mi++)
      #pragma unroll
      for (int ni=0;ni<4;ni++)
        acc[mi][ni] = MFMA16(af[mi], bfr[ni], acc[mi][ni]);
    __builtin_amdgcn_s_setprio(0);
    if (t+1 < nk){
      SCHED0();
      if (t+2 < nk) asm volatile("s_waitcnt vmcnt(3)" ::: "memory");
      else          asm volatile("s_waitcnt vmcnt(0)" ::: "memory");
      SBAR(); SCHED0();
    }
    cur = (cur==2) ? 0 : cur+1;
  }
  int lg = lane >> 4;
  int rbase = m0 + wm + (lg<<2);
  int cbase = n0 + wn + lrow;
  #pragma unroll
  for (int mi=0;mi<4;mi++){
    #pragma unroll
    for (int r=0;r<4;r++){
      int row = rbase + mi*16 + r;
      float rs = 1.f;
      if (MODE==2){
        float rms = sqrtf(rowscale[row]/klim0 + 1e-6f);
        rms = fminf(fmaxf(rms, 1e-6f), 1e6f);
        rs = 1.f/rms;
      }
      #pragma unroll
      for (int ni=0;ni<4;ni++){
        int col = cbase + ni*16;
        float v = acc[mi][ni][r];
        if (MODE==0){
          ((unsigned short*)Cv)[(size_t)row*N + col] = f2bf(v);
        } else if (MODE==1){
          float rv = ((const float*)resv)[(size_t)row*N + col];
          ((unsigned short*)Cv)[(size_t)row*N + col] = f2bf(v + rv);
        } else {
          float rv = bf2f(((const unsigned short*)resv)[(size_t)row*N + col]);
          ((float*)Cv)[(size_t)row*N + col] = v*rs + rv;
        }
      }
    }
  }
}

// ---------------- fused gate+up GEMM (256x128, BK=32, 3-buffer counted vmcnt) ----------------
// hidden = silu(g)*u masked; accumulates per-row sumsq (fp32 atomics).
// Blocks with n0 >= round32(size) write nothing (down-GEMM never reads those cols).
__global__ __launch_bounds__(512) void gateup_kernel(
    const unsigned short* __restrict__ A, const unsigned short* __restrict__ Gt,
    const unsigned short* __restrict__ Ut, unsigned short* __restrict__ Hid,
    const float* __restrict__ scal, float* __restrict__ sumsq){
  __shared__ __align__(16) unsigned short S[49152];  // 3 bufs x 16384 (A 8192|G 4096|U 4096)
  int tid = threadIdx.x;
  int nbx = gridDim.x;
  int id = blockIdx.y * nbx + blockIdx.x;
  int chunk = (nbx * gridDim.y) >> 3;
  int wg = (id & 7) * chunk + (id >> 3);
  int m0 = (wg / nbx) * 256, n0 = (wg % nbx) * 128;
  int size = (int)scal[0];
  int ke = ((size + 31) >> 5) << 5;
  if (n0 >= ke) return;                 // never read downstream
  if (n0 >= size){
    // straddle region [size, ke): must be zero for down-GEMM
    int r = tid >> 1, cb = n0 + (tid&1)*64;
    unsigned short* hp = Hid + (size_t)(m0+r)*Ff + cb;
    bf16x8 z = {};
    #pragma unroll
    for (int i=0;i<8;i++) *(bf16x8*)(hp + i*8) = z;
    return;
  }
  int lane = tid & 63, wave = tid >> 6;
  int wm = (wave>>1)*64, wn = (wave&1)*64;
  int lrow = lane & 15;
  int lksw = (((lane>>4) ^ ((lrow>>1)&3)))*8;
  int segr = lane >> 2;
  int cg = (((lane&3) ^ ((lane>>3)&3))) * 8;
  const unsigned short* gp[4];
  int loff[4];
  #pragma unroll
  for (int i=0;i<4;i++){
    int g = wave*4 + i;
    if (g < 16)      { gp[i] = A  + (size_t)(m0 + g*16 + segr)*Ee + cg;       loff[i] = g*512; }
    else if (g < 24) { gp[i] = Gt + (size_t)(n0 + (g-16)*16 + segr)*Ee + cg;  loff[i] = 8192 + (g-16)*512; }
    else             { gp[i] = Ut + (size_t)(n0 + (g-24)*16 + segr)*Ee + cg;  loff[i] = 12288 + (g-24)*512; }
  }
  f32x4 ag[4][4] = {}, au[4][4] = {};
  #pragma unroll
  for (int i=0;i<4;i++) GLD16(gp[i], &S[loff[i]]);
  #pragma unroll
  for (int i=0;i<4;i++) GLD16(gp[i]+32, &S[16384 + loff[i]]);
  SCHED0();
  asm volatile("s_waitcnt vmcnt(4)" ::: "memory");
  SBAR(); SCHED0();
  int cur = 0;
  for (int t=0; t<32; ++t){
    if (t+2 < 32){
      int stg = cur+2; if (stg>=3) stg-=3;
      int ko = (t+2) << 5;
      #pragma unroll
      for (int i=0;i<4;i++) GLD16(gp[i]+ko, &S[stg*16384 + loff[i]]);
    }
    int base = cur*16384;
    bf16x8 af[4], bg4[4], bu4[4];
    #pragma unroll
    for (int i=0;i<4;i++){
      af[i]  = *(const bf16x8*)&S[base + (wm + i*16 + lrow)*32 + lksw];
      bg4[i] = *(const bf16x8*)&S[base + 8192  + (wn + i*16 + lrow)*32 + lksw];
      bu4[i] = *(const bf16x8*)&S[base + 12288 + (wn + i*16 + lrow)*32 + lksw];
    }
    __builtin_amdgcn_s_setprio(1);
    #pragma unroll
    for (int mi=0;mi<4;mi++)
      #pragma unroll
      for (int ni=0;ni<4;ni++){
        ag[mi][ni] = MFMA16(af[mi], bg4[ni], ag[mi][ni]);
        au[mi][ni] = MFMA16(af[mi], bu4[ni], au[mi][ni]);
      }
    __builtin_amdgcn_s_setprio(0);
    if (t+1 < 32){
      SCHED0();
      if (t+2 < 32) asm volatile("s_waitcnt vmcnt(4)" ::: "memory");
      else          asm volatile("s_waitcnt vmcnt(0)" ::: "memory");
      SBAR(); SCHED0();
    }
    cur = (cur==2) ? 0 : cur+1;
  }
  int lg = lane >> 4;
  int lr = lrow;
  int rbase = m0 + wm + (lg<<2);
  int cbase = n0 + wn + lr;
  #pragma unroll
  for (int mi=0;mi<4;mi++){
    #pragma unroll
    for (int r=0;r<4;r++){
      int row = rbase + mi*16 + r;
      float s4 = 0.f;
      #pragma unroll
      for (int ni=0;ni<4;ni++){
        int col = cbase + ni*16;
        float g = ag[mi][ni][r], u = au[mi][ni][r];
        float hv = (g * (1.f/(1.f+expf(-g)))) * u;
        if (col >= size) hv = 0.f;
        if (__builtin_isnan(hv) || __builtin_isinf(hv)) hv = 0.f;
        Hid[(size_t)row*Ff + col] = f2bf(hv);
        s4 += hv*hv;
      }
      s4 += __shfl_xor(s4, 1);
      s4 += __shfl_xor(s4, 2);
      s4 += __shfl_xor(s4, 4);
      s4 += __shfl_xor(s4, 8);
      if (lr == 0) atomicAdd(&sumsq[row], s4);
    }
  }
}

// ---------------- RoPE + ELU+1 on q,k in bf16 qkv ----------------
__global__ __launch_bounds__(256) void rope_kernel(unsigned short* __restrict__ qkv){
  size_t idx = (size_t)blockIdx.x*256 + threadIdx.x;    // B*L*H*32
  int i = (int)(idx & 31);
  int h = (int)((idx>>5) & 15);
  size_t bl = idx >> 9;
  int pos = (int)(bl & (Ll-1));
  int d0 = 2*i, d1 = d0+1;
  size_t base = bl*3072 + (size_t)h*64 + d0;
  const float LOG1E4_D32 = 0.2878231366242557f;  // ln(10000)/32
  float e0 = (float)(d0 < 32 ? d0 : d0-32);
  float e1 = (float)(d1 < 32 ? d1 : d1-32);
  float f0 = pos * expf(-e0*LOG1E4_D32);
  float f1 = pos * expf(-e1*LOG1E4_D32);
  float s0,c0,s1,c1;
  sincosf(f0,&s0,&c0); sincosf(f1,&s1,&c1);
  unsigned int* qp = (unsigned int*)(qkv + base);
  unsigned int qv = *qp;
  float q0 = bf2f((unsigned short)(qv&0xffff)), q1 = bf2f((unsigned short)(qv>>16));
  float r0 = q0*c0 - q1*s0;
  float r1 = q1*c1 + q0*s1;
  r0 = r0>0.f ? r0+1.f : expf(r0);
  r1 = r1>0.f ? r1+1.f : expf(r1);
  *qp = (unsigned)f2bf(r0) | ((unsigned)f2bf(r1)<<16);
  unsigned int* kp = (unsigned int*)(qkv + base + 1024);
  unsigned int kv = *kp;
  float k0v = bf2f((unsigned short)(kv&0xffff)), k1v = bf2f((unsigned short)(kv>>16));
  float t0 = k0v*c0 - k1v*s0;
  float t1 = k1v*c1 + k0v*s1;
  t0 = t0>0.f ? t0+1.f : expf(t0);
  t1 = t1>0.f ? t1+1.f : expf(t1);
  *kp = (unsigned)f2bf(t0) | ((unsigned)f2bf(t1)<<16);
}

// ---------------- per-chunk K^T V + K col sums via MFMA (ones-column trick) ----------------
__global__ __launch_bounds__(256) void chunksum_kernel(const unsigned short* __restrict__ qkv,
    float* __restrict__ Ssum){
  __shared__ __align__(16) unsigned short Kt[64][72];   // K^T[j][m]
  __shared__ __align__(16) unsigned short Vt[80][72];   // V^T[e][m]; row64=1.0, 65..79=0
  int c = blockIdx.x, bh = blockIdx.y;
  int b = bh >> 4, h = bh & 15;
  int tid = threadIdx.x, lane = tid & 63, wave = tid >> 6;
  int lr = lane & 15, lg = lane >> 4;
  f32x4 acc[5] = {};
  {
    int r16 = tid >> 4, m4 = (tid & 15) * 4;
    unsigned short val = (r16 == 0) ? (unsigned short)0x3F80 : (unsigned short)0;
    #pragma unroll
    for (int u=0; u<4; u++) Vt[64 + r16][m4 + u] = val;
  }
  for (int t=0; t<4; ++t){
    __syncthreads();
    #pragma unroll
    for (int i=0; i<2; i++){
      int tau = tid + i*256;
      int m = tau & 63, dg = (tau >> 6) * 8;
      size_t g = ((size_t)(b*Ll + c*CHk + t*64 + m))*3072 + h*64 + dg;
      bf16x8 kv = *(const bf16x8*)(qkv + g + 1024);
      bf16x8 vv = *(const bf16x8*)(qkv + g + 2048);
      #pragma unroll
      for (int u=0; u<8; u++){
        Kt[dg+u][m] = (unsigned short)kv[u];
        Vt[dg+u][m] = (unsigned short)vv[u];
      }
    }
    __syncthreads();
    #pragma unroll
    for (int kk=0; kk<2; kk++){
      bf16x8 af = *(const bf16x8*)&Kt[wave*16 + lr][kk*32 + lg*8];
      #pragma unroll
      for (int ni=0; ni<5; ni++){
        bf16x8 vf = *(const bf16x8*)&Vt[ni*16 + lr][kk*32 + lg*8];
        acc[ni] = MFMA16(af, vf, acc[ni]);
      }
    }
  }
  float* S = Ssum + ((size_t)bh*NCc + c)*4160;
  int j = wave*16 + lg*4;
  #pragma unroll
  for (int ni=0; ni<4; ni++)
    #pragma unroll
    for (int r=0; r<4; r++)
      S[(size_t)(j+r)*64 + ni*16 + lr] = acc[ni][r];
  if (lr == 0){
    #pragma unroll
    for (int r=0; r<4; r++) S[4096 + j + r] = acc[4][r];
  }
}

// ---------------- exclusive prefix over chunks ----------------
__global__ __launch_bounds__(256) void prefix_kernel(const float* __restrict__ Ssum,
    float* __restrict__ Spre){
  int bh = blockIdx.x; int t = threadIdx.x;
  size_t base = (size_t)bh*NCc*4160;
  for (int e=t; e<4160; e+=256){
    float acc = 0.f;
    #pragma unroll
    for (int c=0;c<NCc;c++){
      Spre[base + (size_t)c*4160 + e] = acc;
      acc += Ssum[base + (size_t)c*4160 + e];
    }
  }
}

// ---------------- per-chunk causal attention via MFMA ----------------
__global__ __launch_bounds__(256, 2) void attnout_kernel(const unsigned short* __restrict__ qkv,
    const float* __restrict__ Spre, unsigned short* __restrict__ attn){
  __shared__ __align__(16) unsigned short SpT[64][72];     // Spre^T[e][j] bf16
  __shared__ __align__(16) unsigned short Ks[64][72];      // K[m][d]
  __shared__ __align__(16) unsigned short Vt[64][72];      // V^T[d][m]
  __shared__ __align__(16) unsigned short P[4][64][72];    // per-wave masked S bf16
  __shared__ float qZd[256];
  int c = blockIdx.x, bh = blockIdx.y;
  int b = bh >> 4, h = bh & 15;
  int tid = threadIdx.x, lane = tid & 63, wave = tid >> 6;
  int lr = lane & 15, lg = lane >> 4;
  const float* Sp = Spre + ((size_t)bh*NCc + c)*4160;

  {
    float zacc = 0.f;
    const unsigned short* qp = qkv + ((size_t)(b*Ll + c*CHk + tid))*3072 + (size_t)h*64;
    #pragma unroll
    for (int g8=0; g8<8; g8++){
      bf16x8 qv = *(const bf16x8*)(qp + g8*8);
      #pragma unroll
      for (int u=0; u<8; u++) zacc += bf2f((unsigned short)qv[u]) * Sp[4096 + g8*8 + u];
    }
    qZd[tid] = zacc;
  }
  #pragma unroll
  for (int i=0; i<2; i++){
    int tau = tid + i*256;
    int j = tau & 63, dg = (tau >> 6) * 8;
    const float* sp = Sp + j*64 + dg;
    #pragma unroll
    for (int u=0; u<8; u++) SpT[dg+u][j] = f2bf(sp[u]);
  }
  bf16x8 af[4][2];
  #pragma unroll
  for (int mi=0; mi<4; mi++){
    size_t qrow = ((size_t)(b*Ll + c*CHk + wave*64 + mi*16 + lr))*3072 + (size_t)h*64;
    #pragma unroll
    for (int kk=0; kk<2; kk++)
      af[mi][kk] = *(const bf16x8*)(qkv + qrow + kk*32 + lg*8);
  }
  __syncthreads();
  f32x4 accO[4][4] = {};
  #pragma unroll
  for (int kk=0; kk<2; kk++){
    #pragma unroll
    for (int ni=0; ni<4; ni++){
      bf16x8 bsp = *(const bf16x8*)&SpT[ni*16 + lr][kk*32 + lg*8];
      #pragma unroll
      for (int mi=0; mi<4; mi++)
        accO[mi][ni] = MFMA16(af[mi][kk], bsp, accO[mi][ni]);
    }
  }
  f32x4 den4[4] = {};
  for (int t=0; t<4; ++t){
    __syncthreads();
    #pragma unroll
    for (int i=0; i<2; i++){
      int tau = tid + i*256;
      int m = tau & 63, dg = (tau >> 6) * 8;
      size_t g = ((size_t)(b*Ll + c*CHk + t*64 + m))*3072 + h*64 + dg;
      *(bf16x8*)&Ks[m][dg] = *(const bf16x8*)(qkv + g + 1024);
      bf16x8 vv = *(const bf16x8*)(qkv + g + 2048);
      #pragma unroll
      for (int u=0; u<8; u++) Vt[dg+u][m] = (unsigned short)vv[u];
    }
    __syncthreads();
    if (wave < t) continue;
    f32x4 sacc[4][4] = {};
    #pragma unroll
    for (int kk=0; kk<2; kk++){
      #pragma unroll
      for (int ni=0; ni<4; ni++){
        bf16x8 kf = *(const bf16x8*)&Ks[ni*16 + lr][kk*32 + lg*8];
        #pragma unroll
        for (int mi=0; mi<4; mi++)
          sacc[mi][ni] = MFMA16(af[mi][kk], kf, sacc[mi][ni]);
      }
    }
    unsigned short (*Pw)[72] = P[wave];
    bool diag = (t == wave);
    #pragma unroll
    for (int mi=0; mi<4; mi++){
      #pragma unroll
      for (int r=0; r<4; r++){
        int q_l = mi*16 + lg*4 + r;
        float rs = 0.f;
        #pragma unroll
        for (int ni=0; ni<4; ni++){
          int m_l = ni*16 + lr;
          float v = sacc[mi][ni][r];
          if (diag && m_l > q_l) v = 0.f;
          rs += v;
          Pw[q_l][m_l] = f2bf(v);
        }
        rs += __shfl_xor(rs, 1);
        rs += __shfl_xor(rs, 2);
        rs += __shfl_xor(rs, 4);
        rs += __shfl_xor(rs, 8);
        den4[mi][r] += rs;
      }
    }
    #pragma unroll
    for (int kk=0; kk<2; kk++){
      bf16x8 pa[4], vf[4];
      #pragma unroll
      for (int mi=0; mi<4; mi++) pa[mi] = *(const bf16x8*)&Pw[mi*16 + lr][kk*32 + lg*8];
      #pragma unroll
      for (int ni=0; ni<4; ni++) vf[ni] = *(const bf16x8*)&Vt[ni*16 + lr][kk*32 + lg*8];
      #pragma unroll
      for (int mi=0; mi<4; mi++)
        #pragma unroll
        for (int ni=0; ni<4; ni++)
          accO[mi][ni] = MFMA16(pa[mi], vf[ni], accO[mi][ni]);
    }
  }
  #pragma unroll
  for (int mi=0; mi<4; mi++){
    #pragma unroll
    for (int r=0; r<4; r++){
      int q_l = mi*16 + lg*4 + r;
      float dtot = den4[mi][r] + qZd[wave*64 + q_l];
      float inv = 1.f / fmaxf(dtot, 1e-6f);
      size_t l = (size_t)(b*Ll + c*CHk + wave*64 + q_l);
      unsigned short* op = attn + l*Ee + h*64 + lr;
      #pragma unroll
      for (int ni=0; ni<4; ni++)
        op[ni*16] = f2bf(accO[mi][ni][r] * inv);
    }
  }
}

// ---------------- column mean over L, deterministic 2-stage ----------------
__global__ __launch_bounds__(256) void colmean1_kernel(const unsigned short* __restrict__ h2,
    float* __restrict__ partial){
  int e = blockIdx.x*256 + threadIdx.x;
  int ly = blockIdx.y;
  int b = blockIdx.z;
  int l0 = ly * 128;
  float s = 0.f;
  for (int l=l0; l<l0+128; l++) s += bf2f(h2[((size_t)(b*Ll + l))*Ee + e]);
  partial[((size_t)(b*32 + ly))*Ee + e] = s;
}
__global__ __launch_bounds__(256) void colmean2_kernel(const float* __restrict__ partial,
    float* __restrict__ xmean){
  int e = blockIdx.x*256 + threadIdx.x;
  int b = blockIdx.y;
  float s = 0.f;
  #pragma unroll
  for (int ly=0; ly<32; ly++) s += partial[((size_t)(b*32 + ly))*Ee + e];
  xmean[b*Ee + e] = s * (1.f/Ll);
}

// ---------------- dim predictor -> floored size ----------------
__global__ __launch_bounds__(256) void dimpred_kernel(const float* __restrict__ xmean,
    const float* __restrict__ w_dp1, const float* __restrict__ w_dp2,
    float* __restrict__ scalars){
  __shared__ float red[256];
  __shared__ float ratio_s[2];
  int t = threadIdx.x;
  for (int b=0;b<2;b++){
    float s = 0.f;
    for (int k=0;k<1024;k++) s += xmean[b*Ee + k] * w_dp1[k*256 + t];
    float sil = s * (1.f/(1.f+expf(-s)));
    red[t] = sil * w_dp2[t];
    __syncthreads();
    for (int off=128; off>0; off>>=1){
      if (t<off) red[t] += red[t+off];
      __syncthreads();
    }
    if (t==0){
      float dr = 1.f/(1.f+expf(-red[0]));
      float ratio = 1.f + (dr-0.5f)*1.0f;       // 2*ADAPT = 1
      ratio = fminf(fmaxf(ratio, 0.5f), 1.5f);
      ratio_s[b] = ratio;
    }
    __syncthreads();
  }
  if (t==0){
    float rm = 0.5f*(ratio_s[0]+ratio_s[1]);
    float size_f = floorf(3072.f * rm);
    if (size_f < 1.f) size_f = 1.f;
    scalars[0] = size_f;
  }
}

extern "C" void kernel_launch(void* const* d_in, const int* in_sizes, int n_in,
                              void* d_out, int out_size, void* d_ws, size_t ws_size,
                              hipStream_t stream){
  const float* x      = (const float*)d_in[0];
  const float* w_qkv  = (const float*)d_in[1];
  const float* w_out  = (const float*)d_in[2];
  const float* g1     = (const float*)d_in[3];
  const float* g2     = (const float*)d_in[4];
  const float* w_dp1  = (const float*)d_in[5];
  const float* w_dp2  = (const float*)d_in[6];
  const float* w_gate = (const float*)d_in[7];
  const float* w_up   = (const float*)d_in[8];
  const float* w_down = (const float*)d_in[9];
  const float* g_hid  = (const float*)d_in[10];
  float* out = (float*)d_out;

  char* w = (char*)d_ws;
  size_t o = 0;
  auto alloc = [&](size_t bytes)->char*{ char* p = w + o; o += (bytes + 255) & ~255ull; return p; };
  unsigned short* R1   = (unsigned short*)alloc((size_t)8192*1024*2);   // h/attn/h2 bf16
  unsigned short* x2b  = (unsigned short*)alloc((size_t)8192*1024*2);   // post-attn residual bf16
  char*           R2   = alloc((size_t)8192*4608*2);                    // qkv bf16 then hidden
  unsigned short* qkvT = (unsigned short*)alloc((size_t)3072*1024*2);
  unsigned short* outT = (unsigned short*)alloc((size_t)1024*1024*2);
  char*           W2   = alloc((size_t)3*4608*1024*2);                  // Ssum/Spre then gateT/upT/downT
  float*       partial = (float*)alloc((size_t)64*1024*4);
  float*         xmean = (float*)alloc(2048*4);
  float*          scal = (float*)alloc(64);
  float*         sumsq = (float*)alloc(8192*4);

  unsigned short* qkv    = (unsigned short*)R2;
  unsigned short* hidden = (unsigned short*)R2;
  float* Ssum = (float*)W2;
  float* Spre = Ssum + (size_t)512*4160;
  unsigned short* gateT = (unsigned short*)W2;
  unsigned short* upT   = gateT + (size_t)4608*1024;
  unsigned short* downT = upT   + (size_t)4608*1024;

  wconv_kernel<<<dim3(3072/64, 1024/64),256,0,stream>>>(w_qkv, qkvT, 1024, 3072, nullptr);
  wconv_kernel<<<dim3(1024/64, 1024/64),256,0,stream>>>(w_out, outT, 1024, 1024, nullptr);

  rmsnorm_kernel<<<8192,256,0,stream>>>(x, g1, R1);
  gemm_kernel<0><<<dim3(3072/128, 8192/256),512,0,stream>>>(R1, qkvT, qkv,
      8192,3072,1024, nullptr,nullptr,nullptr);
  rope_kernel<<<16384,256,0,stream>>>(qkv);
  chunksum_kernel<<<dim3(NCc,Bb*Hh),256,0,stream>>>(qkv, Ssum);
  prefix_kernel<<<Bb*Hh,256,0,stream>>>(Ssum, Spre);
  attnout_kernel<<<dim3(NCc,Bb*Hh),256,0,stream>>>(qkv, Spre, R1);

  wconv_kernel<<<dim3(4608/64, 1024/64),256,0,stream>>>(w_gate, gateT, 1024, 4608, nullptr);
  wconv_kernel<<<dim3(4608/64, 1024/64),256,0,stream>>>(w_up,   upT,   1024, 4608, nullptr);
  wconv_kernel<<<dim3(1024/64, 4608/64),256,0,stream>>>(w_down, downT, 4608, 1024, g_hid);

  gemm_kernel<1><<<dim3(1024/128, 8192/256),512,0,stream>>>(R1, outT, x2b,
      8192,1024,1024, x,nullptr,nullptr);
  rmsnorm_b_kernel<<<8192,256,0,stream>>>(x2b, g2, R1);
  colmean1_kernel<<<dim3(4,32,2),256,0,stream>>>(R1, partial);
  colmean2_kernel<<<dim3(4,2),256,0,stream>>>(partial, xmean);
  dimpred_kernel<<<1,256,0,stream>>>(xmean, w_dp1, w_dp2, scal);
  hipMemsetAsync(sumsq, 0, 8192*sizeof(float), stream);
  gateup_kernel<<<dim3(4608/128, 8192/256),512,0,stream>>>(R1, gateT, upT, hidden, scal, sumsq);
  gemm_kernel<2><<<dim3(1024/128, 8192/256),512,0,stream>>>(hidden, downT, out,
      8192,1024,4608, x2b, sumsq, scal);
}